// Round 8
// baseline (316.328 us; speedup 1.0000x reference)
//
#include <hip/hip_runtime.h>

typedef unsigned short ushort_t;
typedef unsigned int uint32;

#define N_NODES 10000
#define N_EDGES 160000
#define ET (N_NODES + N_EDGES)   /* 170000 edges incl self-loops */
#define MPAD 10112               /* 79 * 128 */
#define HT 1024                  /* heads * hid */
#define HEADS 8
#define NEG 0.2f

/* ---- ws layout (bytes, 256-aligned) ---- */
#define O_FLAG     0             /* flags[0]=edge64, flags[1]=inputs_f32 */
#define O_SRC      256
#define O_DST      (O_SRC + 680192)
#define O_COUNTS   (O_DST + 680192)
#define O_OFFS     (O_COUNTS + 40192)
#define O_CURS     (O_OFFS + 40192)
#define O_SSORT    (O_CURS + 40192)
#define O_ALS      (O_SSORT + 680192)
#define O_ALD      (O_ALS + 320000)
#define O_AL3S     (O_ALD + 320000)
#define O_AL3D     (O_AL3S + 40192)
#define O_H3       (O_AL3D + 40192)
#define O_XF       (O_H3 + 160000)      /* x fp32: 140000 floats */
#define O_W1F      (O_XF + 560128)      /* 14336 floats */
#define O_AS1F     (O_W1F + 57344)      /* 6 x 1024 floats: as1,ad1,b1,as2,ad2,b2 */
#define O_W3F      (O_AS1F + 24576)     /* 4096 floats */
#define O_S3F      (O_W3F + 16384)      /* as3 @0, ad3 @+16 floats, b3 @+32 floats */
#define O_W2T      (O_S3F + 768)        /* bf16 [1024,1024] transposed */
#define O_BUFA     (O_W2T + 2097152)
#define O_BUFB     (O_BUFA + 20709376)

__device__ __forceinline__ float bf2f(ushort_t u){ return __uint_as_float(((uint32)u) << 16); }
__device__ __forceinline__ ushort_t f2bf(float f){
    uint32 x = __float_as_uint(f);
    return (ushort_t)((x + 0x7fffu + ((x >> 16) & 1u)) >> 16);
}
__device__ __forceinline__ void unpack2(uint32 u, float& lo, float& hi){
    lo = __uint_as_float(u << 16);
    hi = __uint_as_float(u & 0xffff0000u);
}

typedef __bf16 bf16x8 __attribute__((ext_vector_type(8)));
typedef float  f32x4  __attribute__((ext_vector_type(4)));

typedef const __attribute__((address_space(1))) uint32* gas1_u32;
typedef       __attribute__((address_space(3))) uint32* las3_u32;

__device__ __forceinline__ void gload_lds16(const void* g, void* l){
    __builtin_amdgcn_global_load_lds((gas1_u32)g, (las3_u32)l, 16, 0, 0);
}

/* inline dtype probes: bf16 low-element exponent field concentrates near 127;
   fp32 low 16 bits are uniform mantissa bits. */
__device__ __forceinline__ int probe_f32(const uint32* __restrict__ w){
    int cnt = 0;
    for (int i = 0; i < 256; i++){
        uint32 e = (w[i] >> 7) & 0xffu;
        cnt += (e >= 64u && e <= 160u) ? 1 : 0;
    }
    return (cnt > 200) ? 0 : 1;
}
__device__ __forceinline__ int probe_edge64(const int* __restrict__ ei){
    int nz = 0;
    for (int i = 0; i < 128; i++) nz |= ei[2*i + 1];
    return (nz == 0) ? 1 : 0;
}

/* ---------------- k_setup ---------------- */
struct CvtArgs {
    const void* src[12];
    float*      dst[12];
    int         n[12];
};

__global__ __launch_bounds__(256) void k_setup(CvtArgs a, const void* __restrict__ W2,
                                               const uint32* __restrict__ w1raw,
                                               const int* __restrict__ eiraw,
                                               int* __restrict__ counts,
                                               ushort_t* __restrict__ W2T,
                                               int* __restrict__ flags){
    __shared__ ushort_t tile[32][33];
    int slice = blockIdx.y;
    int tid = threadIdx.x;
    if (slice < 12){
        int n = a.n[slice];
        int base = blockIdx.x * 1024 + tid * 4;
        if (base >= n) return;
        int f32 = probe_f32(w1raw);
        const void* s = a.src[slice];
        float* d = a.dst[slice];
        #pragma unroll
        for (int j = 0; j < 4; j++){
            int i = base + j;
            if (i < n) d[i] = f32 ? ((const float*)s)[i] : bf2f(((const ushort_t*)s)[i]);
        }
    } else if (slice == 12){
        if (blockIdx.x == 10){
            if (tid == 0) flags[0] = probe_edge64(eiraw);
            if (tid == 1) flags[1] = probe_f32(w1raw);
            return;
        }
        if (blockIdx.x < 10){
            int i0 = blockIdx.x * 1024 + tid * 4;
            if (i0 + 3 < N_NODES){
                *(int4*)(counts + i0) = make_int4(0,0,0,0);
            } else {
                for (int j = 0; j < 4; j++) if (i0 + j < N_NODES) counts[i0 + j] = 0;
            }
        }
    } else {
        int f32 = probe_f32(w1raw);
        int bx = blockIdx.x & 31, by = blockIdx.x >> 5;
        int cx = tid & 31;
        int ry = (tid >> 5) * 4;
        #pragma unroll
        for (int r = 0; r < 4; r++){
            size_t idx = (size_t)(by*32 + ry + r)*1024 + bx*32 + cx;
            tile[ry + r][cx] = f32 ? f2bf(((const float*)W2)[idx]) : ((const ushort_t*)W2)[idx];
        }
        __syncthreads();
        #pragma unroll
        for (int r = 0; r < 4; r++)
            W2T[(size_t)(bx*32 + ry + r)*1024 + by*32 + cx] = tile[cx][ry + r];
    }
}

/* ---------------- extract edges (+self-loops) as int32, fused histogram ---------------- */
__global__ __launch_bounds__(256) void k_extract_hist(const void* __restrict__ ei, const int* __restrict__ flags,
                                                      int* __restrict__ src, int* __restrict__ dst,
                                                      int* __restrict__ counts){
    int i = blockIdx.x * 256 + threadIdx.x;
    int is64 = flags[0];
    int s = -1, d = -1;
    if (i < N_EDGES){
        if (is64){
            const long long* p = (const long long*)ei;
            s = (int)p[i]; d = (int)p[N_EDGES + i];
        } else {
            const int* p = (const int*)ei;
            s = p[i]; d = p[N_EDGES + i];
        }
    } else if (i < ET){
        s = i - N_EDGES; d = s;
    }
    if (d >= 0){
        src[i] = s; dst[i] = d;
        atomicAdd(&counts[d], 1);
    }
}

/* single-block exclusive scan over N_NODES counts -> offs + cursors */
__global__ __launch_bounds__(1024) void k_scan(const int* __restrict__ counts, int* __restrict__ offs,
                                               int* __restrict__ cursors, int n){
    __shared__ int wsum[16];
    __shared__ int running_s;
    int tid = threadIdx.x;
    int lane = tid & 63, wid = tid >> 6;
    if (tid == 0) running_s = 0;
    __syncthreads();
    for (int base = 0; base < n; base += 1024){
        int i = base + tid;
        int v = (i < n) ? counts[i] : 0;
        int x = v;
        #pragma unroll
        for (int d = 1; d < 64; d <<= 1){
            int t = __shfl_up(x, d, 64);
            if (lane >= d) x += t;
        }
        if (lane == 63) wsum[wid] = x;
        __syncthreads();
        if (wid == 0 && lane < 16){
            int w = wsum[lane];
            #pragma unroll
            for (int d = 1; d < 16; d <<= 1){
                int t = __shfl_up(w, d, 64);
                if (lane >= d) w += t;
            }
            wsum[lane] = w;
        }
        __syncthreads();
        int wprefix = (wid == 0) ? 0 : wsum[wid - 1];
        int run = running_s;
        int excl = run + wprefix + (x - v);
        if (i < n){ offs[i] = excl; cursors[i] = excl; }
        __syncthreads();
        if (tid == 0) running_s = run + wsum[15];
        __syncthreads();
    }
    if (tid == 0) offs[n] = running_s;
}

__global__ __launch_bounds__(256) void k_scatter(const int* __restrict__ src, const int* __restrict__ dst,
                                                 int* __restrict__ cursors, int* __restrict__ ssort){
    int i = blockIdx.x * 256 + threadIdx.x;
    if (i < ET){
        int pos = atomicAdd(&cursors[dst[i]], 1);
        ssort[pos] = src[i];
    }
}

/* ---------------- layer-1 GEMM fused with attention dots ---------------- */
__global__ __launch_bounds__(256) void k_gemm1f(const float* __restrict__ x, const float* __restrict__ W1,
                                                const float* __restrict__ a_src, const float* __restrict__ a_dst,
                                                ushort_t* __restrict__ h1,
                                                float* __restrict__ alS, float* __restrict__ alD){
    __shared__ float w1s[14 * HT];
    int tid = threadIdx.x;
    for (int i = tid * 4; i < 14 * HT; i += 1024)
        *(float4*)(w1s + i) = *(const float4*)(W1 + i);
    int c0 = tid * 4;
    float4 sv = *(const float4*)(a_src + c0);
    float4 dv = *(const float4*)(a_dst + c0);
    int head = tid >> 5, l32 = tid & 31;
    __syncthreads();
    for (int n = blockIdx.x; n < N_NODES; n += gridDim.x){
        float a0=0.f, a1=0.f, a2=0.f, a3=0.f;
        #pragma unroll
        for (int k = 0; k < 14; k++){
            float xv = x[n*14 + k];
            float4 w = *(const float4*)(w1s + k*HT + c0);
            a0 += xv*w.x; a1 += xv*w.y; a2 += xv*w.z; a3 += xv*w.w;
        }
        uint2 o;
        o.x = (uint32)f2bf(a0) | ((uint32)f2bf(a1) << 16);
        o.y = (uint32)f2bf(a2) | ((uint32)f2bf(a3) << 16);
        *(uint2*)(h1 + (size_t)n*HT + c0) = o;
        float h0,h1v,h2,h3v;
        unpack2(o.x, h0, h1v); unpack2(o.y, h2, h3v);
        float s = h0*sv.x + h1v*sv.y + h2*sv.z + h3v*sv.w;
        float d = h0*dv.x + h1v*dv.y + h2*dv.z + h3v*dv.w;
        #pragma unroll
        for (int of = 16; of; of >>= 1){ s += __shfl_xor(s, of, 32); d += __shfl_xor(d, of, 32); }
        if (l32 == 0){ alS[n*HEADS + head] = s; alD[n*HEADS + head] = d; }
    }
}

/* ---------------- fused segment-softmax + aggregate + bias + relu (v5.2) ----------------
   Head-partitioned, XCD-affine gather (see R4/R5): block b -> head = b&7, each
   XCD reads only H columns [128h,128h+128) = 2.56 MB (FETCH 146->15.7 MB, proven).
   v5.2 (T13 defer-max): regime is now VALU-bound (VALUBusy 92%) so cut the
   hot-loop instruction count: conditional rescale (only when max grows —
   16-lane-subgroup-uniform branch, decaying frequency) instead of
   always-rescale. Common path: 2 FMA/channel + 2 exp vs mul+2FMA + 3 exp. */
__global__ __launch_bounds__(256) void k_gat_agg(const ushort_t* __restrict__ H, const float* __restrict__ alS,
                                                 const float* __restrict__ alD, const int* __restrict__ offs,
                                                 const int* __restrict__ srcs, const float* __restrict__ bias,
                                                 ushort_t* __restrict__ out){
    int tid = threadIdx.x;
    int wv = tid >> 6, lane = tid & 63;
    int head = blockIdx.x & 7;
    int n = (blockIdx.x >> 3) * 4 + wv;
    if (n >= N_NODES) return;
    int beg = offs[n], end = offs[n+1];
    int g = lane >> 4;           /* edge slot 0..3 */
    int q = lane & 15;           /* 8-channel sub-block within head */
    float ad = alD[n*HEADS + head];
    const ushort_t* Hh = H + head*128 + q*8;
    const float NINF = -__int_as_float(0x7f800000);

    float m = -1e30f, z = 0.f;
    float c0=0.f,c1=0.f,c2=0.f,c3=0.f,c4=0.f,c5=0.f,c6=0.f,c7=0.f;
    for (int c = beg; c < end; c += 64){
        int cn = min(64, end - c);
        int sreg = (lane < cn) ? srcs[c + lane] : 0;
        int j = 0;
        /* 8-edge body: e1 = j+4+g <= j+7 < cn, so no masking needed */
        for (; j + 8 <= cn; j += 8){
            int s0 = __shfl(sreg, j + g, 64);
            int s1 = __shfl(sreg, j + 4 + g, 64);
            uint4 u0 = *(const uint4*)(Hh + (size_t)s0*HT);
            uint4 u1 = *(const uint4*)(Hh + (size_t)s1*HT);
            float v0 = alS[s0*HEADS + head] + ad; v0 = v0 > 0.f ? v0 : NEG*v0;
            float v1 = alS[s1*HEADS + head] + ad; v1 = v1 > 0.f ? v1 : NEG*v1;
            float vm = fmaxf(v0, v1);
            if (vm > m){                     /* rare after warmup; subgroup-uniform */
                float sc = __expf(m - vm);
                z *= sc;
                c0*=sc; c1*=sc; c2*=sc; c3*=sc;
                c4*=sc; c5*=sc; c6*=sc; c7*=sc;
                m = vm;
            }
            float w0 = __expf(v0 - m);
            float w1 = __expf(v1 - m);
            z += (w0 + w1);
            float f0,f1,f2,f3,f4,f5,f6,f7;
            float g0,g1,g2,g3,g4,g5,g6,g7;
            unpack2(u0.x,f0,f1); unpack2(u0.y,f2,f3); unpack2(u0.z,f4,f5); unpack2(u0.w,f6,f7);
            unpack2(u1.x,g0,g1); unpack2(u1.y,g2,g3); unpack2(u1.z,g4,g5); unpack2(u1.w,g6,g7);
            c0 = fmaf(w0,f0, fmaf(w1,g0, c0));
            c1 = fmaf(w0,f1, fmaf(w1,g1, c1));
            c2 = fmaf(w0,f2, fmaf(w1,g2, c2));
            c3 = fmaf(w0,f3, fmaf(w1,g3, c3));
            c4 = fmaf(w0,f4, fmaf(w1,g4, c4));
            c5 = fmaf(w0,f5, fmaf(w1,g5, c5));
            c6 = fmaf(w0,f6, fmaf(w1,g6, c6));
            c7 = fmaf(w0,f7, fmaf(w1,g7, c7));
        }
        /* masked tail, 4 edges at a time */
        for (; j < cn; j += 4){
            int e = j + g;
            int s0 = __shfl(sreg, e, 64);
            uint4 u0 = *(const uint4*)(Hh + (size_t)s0*HT);
            float v0 = alS[s0*HEADS + head] + ad; v0 = v0 > 0.f ? v0 : NEG*v0;
            v0 = (e < cn) ? v0 : NINF;          /* exp(NINF - finite) == 0 */
            if (v0 > m){
                float sc = __expf(m - v0);
                z *= sc;
                c0*=sc; c1*=sc; c2*=sc; c3*=sc;
                c4*=sc; c5*=sc; c6*=sc; c7*=sc;
                m = v0;
            }
            float w0 = __expf(v0 - m);
            z += w0;
            float f0,f1,f2,f3,f4,f5,f6,f7;
            unpack2(u0.x,f0,f1); unpack2(u0.y,f2,f3); unpack2(u0.z,f4,f5); unpack2(u0.w,f6,f7);
            c0 = fmaf(w0,f0, c0); c1 = fmaf(w0,f1, c1);
            c2 = fmaf(w0,f2, c2); c3 = fmaf(w0,f3, c3);
            c4 = fmaf(w0,f4, c4); c5 = fmaf(w0,f5, c5);
            c6 = fmaf(w0,f6, c6); c7 = fmaf(w0,f7, c7);
        }
    }
    /* merge (m,z,c[8]) across the 4 edge-groups: xor 16 then 32 */
    #pragma unroll
    for (int off = 16; off < 64; off <<= 1){
        float m2 = __shfl_xor(m, off, 64);
        float z2 = __shfl_xor(z, off, 64);
        float d0 = __shfl_xor(c0, off, 64);
        float d1 = __shfl_xor(c1, off, 64);
        float d2 = __shfl_xor(c2, off, 64);
        float d3 = __shfl_xor(c3, off, 64);
        float d4 = __shfl_xor(c4, off, 64);
        float d5 = __shfl_xor(c5, off, 64);
        float d6 = __shfl_xor(c6, off, 64);
        float d7 = __shfl_xor(c7, off, 64);
        float nm = fmaxf(m, m2);
        float a = __expf(m - nm), b = __expf(m2 - nm);
        z = z*a + z2*b;
        c0 = c0*a + d0*b; c1 = c1*a + d1*b;
        c2 = c2*a + d2*b; c3 = c3*a + d3*b;
        c4 = c4*a + d4*b; c5 = c5*a + d5*b;
        c6 = c6*a + d6*b; c7 = c7*a + d7*b;
        m = nm;
    }
    if (g == 0){
        float inv = 1.f / (z + 1e-16f);
        int ch0 = head*128 + q*8;
        float4 b0 = *(const float4*)(bias + ch0);
        float4 b1 = *(const float4*)(bias + ch0 + 4);
        c0 = fmaxf(c0*inv+b0.x, 0.f); c1 = fmaxf(c1*inv+b0.y, 0.f);
        c2 = fmaxf(c2*inv+b0.z, 0.f); c3 = fmaxf(c3*inv+b0.w, 0.f);
        c4 = fmaxf(c4*inv+b1.x, 0.f); c5 = fmaxf(c5*inv+b1.y, 0.f);
        c6 = fmaxf(c6*inv+b1.z, 0.f); c7 = fmaxf(c7*inv+b1.w, 0.f);
        uint4 o;
        o.x = (uint32)f2bf(c0) | ((uint32)f2bf(c1) << 16);
        o.y = (uint32)f2bf(c2) | ((uint32)f2bf(c3) << 16);
        o.z = (uint32)f2bf(c4) | ((uint32)f2bf(c5) << 16);
        o.w = (uint32)f2bf(c6) | ((uint32)f2bf(c7) << 16);
        *(uint4*)(out + (size_t)n*HT + ch0) = o;
    }
}

/* ---------------- layer-2 GEMM: bf16 MFMA, fused attention dots (v4) ----------------
   8 waves (512 threads), wave owns 64x32 of the 128x128 tile (R5: doubled
   resident waves at identical LDS; gemm2 dropped out of top-5). BK=64 2-phase
   double-buffered pipeline; attention-dot epilogue combines 4 wn-waves via
   LDS partials (aliased into lbuf, barrier-separated). */
__global__ __launch_bounds__(512) void k_gemm2(const ushort_t* __restrict__ A, const ushort_t* __restrict__ BT,
                                               ushort_t* __restrict__ C,
                                               const float* __restrict__ aS, const float* __restrict__ aD,
                                               float* __restrict__ alS, float* __restrict__ alD){
    __shared__ ushort_t lbuf[2][2][128*64];       /* [buf][0=A,1=B][row*64+e] : 64 KiB */
    float (*reds)[3][64][2] = (float (*)[3][64][2])lbuf; /* [wm6][widx][rl][s/d], aliased after K-loop */
    int L = blockIdx.x;
    int xcd = L & 7;
    int wi  = L >> 3;
    int bm  = xcd * 10 + (wi >> 3);
    int bn  = wi & 7;
    if (bm >= 79) return;
    int tid = threadIdx.x;
    int lane = tid & 63;
    int wave = tid >> 6;                  /* 0..7 */
    int wm  = (wave & 1) * 64;            /* row half */
    int wn32 = (wave >> 1) * 32;          /* 32-col strip */
    int lm = lane & 15, kg = lane >> 4;
    int c0 = (kg ^ (lm & 7)) * 8;    /* phys elem offset of ksub0 fragment; ksub1 = c0^32 */
    f32x4 acc[4][2];
    #pragma unroll
    for (int i = 0; i < 4; i++)
        #pragma unroll
        for (int j = 0; j < 2; j++) acc[i][j] = (f32x4)0.0f;

    const int K = 1024;
    int rowA0 = bm * 128, rowB0 = bn * 128;

    auto stage = [&](int buf, int k0){
        #pragma unroll
        for (int it = 0; it < 2; ++it){
            int s = tid + it*512;           /* chunk id in [0,1024): row = s>>3, phys chunk = s&7 */
            int r = s >> 3;
            int q = (s & 7) ^ (r & 7);      /* logical chunk living at this phys slot */
            gload_lds16(A  + (size_t)(rowA0 + r)*K + k0 + q*8, &lbuf[buf][0][s*8]);
            gload_lds16(BT + (size_t)(rowB0 + r)*K + k0 + q*8, &lbuf[buf][1][s*8]);
        }
    };

    stage(0, 0);
    asm volatile("s_waitcnt vmcnt(0)" ::: "memory");
    __syncthreads();
    int cur = 0;
    for (int k0 = 0; k0 < K; k0 += 64){
        if (k0 + 64 < K) stage(cur ^ 1, k0 + 64);   /* prefetch next tile first */
        bf16x8 a0[4], a1[4], b0[2], b1[2];
        #pragma unroll
        for (int mt = 0; mt < 4; mt++){
            const ushort_t* base = &lbuf[cur][0][(wm + mt*16 + lm)*64];
            a0[mt] = *(const bf16x8*)(base + c0);
            a1[mt] = *(const bf16x8*)(base + (c0 ^ 32));
        }
        #pragma unroll
        for (int nt = 0; nt < 2; nt++){
            const ushort_t* base = &lbuf[cur][1][(wn32 + nt*16 + lm)*64];
            b0[nt] = *(const bf16x8*)(base + c0);
            b1[nt] = *(const bf16x8*)(base + (c0 ^ 32));
        }
        #pragma unroll
        for (int mt = 0; mt < 4; mt++)
            #pragma unroll
            for (int nt = 0; nt < 2; nt++)
                acc[mt][nt] = __builtin_amdgcn_mfma_f32_16x16x32_bf16(a0[mt], b0[nt], acc[mt][nt], 0, 0, 0);
        #pragma unroll
        for (int mt = 0; mt < 4; mt++)
            #pragma unroll
            for (int nt = 0; nt < 2; nt++)
                acc[mt][nt] = __builtin_amdgcn_mfma_f32_16x16x32_bf16(a1[mt], b1[nt], acc[mt][nt], 0, 0, 0);
        asm volatile("s_waitcnt vmcnt(0)" ::: "memory");
        __syncthreads();
        cur ^= 1;
    }
    #pragma unroll
    for (int mt = 0; mt < 4; mt++){
        int row_base = bm*128 + wm + mt*16 + kg*4;
        #pragma unroll
        for (int nt = 0; nt < 2; nt++){
            int col = bn*128 + wn32 + nt*16 + lm;
            #pragma unroll
            for (int r = 0; r < 4; r++){
                int row = row_base + r;
                if (row < N_NODES) C[(size_t)row*HT + col] = f2bf(acc[mt][nt][r]);
            }
        }
    }
    /* fused attention-dot epilogue for head bn: wave partial over its 32 cols,
       combine 4 wn-waves through LDS partials */
    float as_l[2], ad_l[2];
    #pragma unroll
    for (int nt = 0; nt < 2; nt++){
        as_l[nt] = aS[bn*128 + wn32 + nt*16 + lm];
        ad_l[nt] = aD[bn*128 + wn32 + nt*16 + lm];
    }
    float psA[4][4], pdA[4][4];
    #pragma unroll
    for (int mt = 0; mt < 4; mt++){
        #pragma unroll
        for (int r = 0; r < 4; r++){
            float ps = acc[mt][0][r]*as_l[0] + acc[mt][1][r]*as_l[1];
            float pd = acc[mt][0][r]*ad_l[0] + acc[mt][1][r]*ad_l[1];
            #pragma unroll
            for (int o = 1; o < 16; o <<= 1){ ps += __shfl_xor(ps, o, 64); pd += __shfl_xor(pd, o, 64); }
            psA[mt][r] = ps; pdA[mt][r] = pd;
            if (wn32 != 0 && lm == 0){
                int rl = mt*16 + kg*4 + r;
                reds[wm >> 6][(wn32 >> 5) - 1][rl][0] = ps;
                reds[wm >> 6][(wn32 >> 5) - 1][rl][1] = pd;
            }
        }
    }
    __syncthreads();
    if (wn32 == 0 && lm == 0){
        #pragma unroll
        for (int mt = 0; mt < 4; mt++){
            #pragma unroll
            for (int r = 0; r < 4; r++){
                int rl = mt*16 + kg*4 + r;
                int row = bm*128 + wm + rl;
                if (row < N_NODES){
                    alS[row*HEADS + bn] = psA[mt][r] + reds[wm >> 6][0][rl][0]
                                        + reds[wm >> 6][1][rl][0] + reds[wm >> 6][2][rl][0];
                    alD[row*HEADS + bn] = pdA[mt][r] + reds[wm >> 6][0][rl][1]
                                        + reds[wm >> 6][1][rl][1] + reds[wm >> 6][2][rl][1];
                }
            }
        }
    }
}

/* ---------------- layer-3 GEMM: wave-per-node, W3 in registers ---------------- */
__global__ __launch_bounds__(256) void k_gemm3(const ushort_t* __restrict__ A, const float* __restrict__ W3,
                                               const float* __restrict__ s3,
                                               float* __restrict__ h3, float* __restrict__ al3s, float* __restrict__ al3d){
    int tid = threadIdx.x;
    int lane = tid & 63, wave = tid >> 6;
    int n = blockIdx.x * 4 + wave;
    if (n >= N_NODES) return;
    float4 w3r[16];
    #pragma unroll
    for (int j = 0; j < 16; j++) w3r[j] = ((const float4*)W3)[lane*16 + j];
    const uint4* ap = (const uint4*)(A + (size_t)n*HT + lane*16);
    uint4 u0 = ap[0], u1 = ap[1];
    uint32 uu[8] = {u0.x,u0.y,u0.z,u0.w,u1.x,u1.y,u1.z,u1.w};
    float acc0=0.f, acc1=0.f, acc2=0.f, acc3=0.f;
    #pragma unroll
    for (int p = 0; p < 8; p++){
        float lo, hi;
        unpack2(uu[p], lo, hi);
        float4 wl = w3r[p*2], wh = w3r[p*2+1];
        acc0 += lo*wl.x + hi*wh.x;
        acc1 += lo*wl.y + hi*wh.y;
        acc2 += lo*wl.z + hi*wh.z;
        acc3 += lo*wl.w + hi*wh.w;
    }
    #pragma unroll
    for (int o = 32; o; o >>= 1){
        acc0 += __shfl_xor(acc0, o, 64); acc1 += __shfl_xor(acc1, o, 64);
        acc2 += __shfl_xor(acc2, o, 64); acc3 += __shfl_xor(acc3, o, 64);
    }
    if (lane == 0){
        *(float4*)(h3 + n*4) = make_float4(acc0, acc1, acc2, acc3);
        al3s[n] = acc0*s3[0] + acc1*s3[1] + acc2*s3[2] + acc3*s3[3];
        al3d[n] = acc0*s3[16] + acc1*s3[17] + acc2*s3[18] + acc3*s3[19];
    }
}

/* ---------------- layer-3 attention aggregate: wave-per-node ---------------- */
__global__ __launch_bounds__(256) void k_gat_agg3(const float* __restrict__ h3, const float* __restrict__ al3s,
                                                  const float* __restrict__ al3d, const int* __restrict__ offs,
                                                  const int* __restrict__ srcs, const float* __restrict__ b3,
                                                  const int* __restrict__ flags, void* __restrict__ out){
    int tid = threadIdx.x;
    int l = tid & 63, wave = tid >> 6;
    int n = blockIdx.x * 4 + wave;
    if (n >= N_NODES) return;
    int beg = offs[n], end = offs[n+1];
    float ad = al3d[n];
    float m = -1e30f;
    for (int e = beg + l; e < end; e += 64){
        float v = al3s[srcs[e]] + ad; v = v > 0.f ? v : NEG*v;
        m = fmaxf(m, v);
    }
    #pragma unroll
    for (int o = 32; o; o >>= 1) m = fmaxf(m, __shfl_xor(m, o, 64));
    float z = 0.f;
    for (int e = beg + l; e < end; e += 64){
        float v = al3s[srcs[e]] + ad; v = v > 0.f ? v : NEG*v;
        z += __expf(v - m);
    }
    #pragma unroll
    for (int o = 32; o; o >>= 1) z += __shfl_xor(z, o, 64);
    float inv = 1.f / (z + 1e-16f);
    float a0=0.f, a1=0.f, a2=0.f, a3=0.f;
    for (int e = beg + l; e < end; e += 64){
        int s = srcs[e];
        float v = al3s[s] + ad; v = v > 0.f ? v : NEG*v;
        float w = __expf(v - m) * inv;
        float4 hv = *(const float4*)(h3 + s*4);
        a0 += w*hv.x; a1 += w*hv.y; a2 += w*hv.z; a3 += w*hv.w;
    }
    #pragma unroll
    for (int o = 32; o; o >>= 1){
        a0 += __shfl_xor(a0, o, 64); a1 += __shfl_xor(a1, o, 64);
        a2 += __shfl_xor(a2, o, 64); a3 += __shfl_xor(a3, o, 64);
    }
    if (l == 0){
        float r0 = fmaxf(a0 + b3[0], 0.f);
        float r1 = fmaxf(a1 + b3[1], 0.f);
        float r2 = fmaxf(a2 + b3[2], 0.f);
        float r3 = fmaxf(a3 + b3[3], 0.f);
        if (flags[1]){
            float* o4 = (float*)out;
            o4[n*4+0]=r0; o4[n*4+1]=r1; o4[n*4+2]=r2; o4[n*4+3]=r3;
        } else {
            ushort_t* o2 = (ushort_t*)out;
            o2[n*4+0]=f2bf(r0); o2[n*4+1]=f2bf(r1); o2[n*4+2]=f2bf(r2); o2[n*4+3]=f2bf(r3);
        }
    }
}

extern "C" void kernel_launch(void* const* d_in, const int* in_sizes, int n_in,
                              void* d_out, int out_size, void* d_ws, size_t ws_size,
                              hipStream_t stream){
    const void* x   = d_in[0];
    const void* ei  = d_in[1];
    const void* W1  = d_in[2];
    const void* as1 = d_in[3];
    const void* ad1 = d_in[4];
    const void* b1  = d_in[5];
    const void* W2  = d_in[6];
    const void* as2 = d_in[7];
    const void* ad2 = d_in[8];
    const void* b2  = d_in[9];
    const void* W3  = d_in[10];
    const void* as3 = d_in[11];
    const void* ad3 = d_in[12];
    const void* b3  = d_in[13];

    char* ws = (char*)d_ws;
    int* flags     = (int*)(ws + O_FLAG);
    int* srcA      = (int*)(ws + O_SRC);
    int* dstA      = (int*)(ws + O_DST);
    int* counts    = (int*)(ws + O_COUNTS);
    int* offs      = (int*)(ws + O_OFFS);
    int* cursors   = (int*)(ws + O_CURS);
    int* ssort     = (int*)(ws + O_SSORT);
    float* alS     = (float*)(ws + O_ALS);
    float* alD     = (float*)(ws + O_ALD);
    float* al3s    = (float*)(ws + O_AL3S);
    float* al3d    = (float*)(ws + O_AL3D);
    float* h3      = (float*)(ws + O_H3);
    float* xF      = (float*)(ws + O_XF);
    float* W1F     = (float*)(ws + O_W1F);
    float* wvecF   = (float*)(ws + O_AS1F);
    float* W3F     = (float*)(ws + O_W3F);
    float* s3F     = (float*)(ws + O_S3F);
    ushort_t* W2T  = (ushort_t*)(ws + O_W2T);
    ushort_t* bufA = (ushort_t*)(ws + O_BUFA);
    ushort_t* bufB = (ushort_t*)(ws + O_BUFB);

    const int EB = (ET + 255) / 256;

    CvtArgs ca;
    ca.src[0]=x;   ca.dst[0]=xF;            ca.n[0]=140000;
    ca.src[1]=W1;  ca.dst[1]=W1F;           ca.n[1]=14336;
    ca.src[2]=as1; ca.dst[2]=wvecF+0*1024;  ca.n[2]=1024;
    ca.src[3]=ad1; ca.dst[3]=wvecF+1*1024;  ca.n[3]=1024;
    ca.src[4]=b1;  ca.dst[4]=wvecF+2*1024;  ca.n[4]=1024;
    ca.src[5]=as2; ca.dst[5]=wvecF+3*1024;  ca.n[5]=1024;
    ca.src[6]=ad2; ca.dst[6]=wvecF+4*1024;  ca.n[6]=1024;
    ca.src[7]=b2;  ca.dst[7]=wvecF+5*1024;  ca.n[7]=1024;
    ca.src[8]=W3;  ca.dst[8]=W3F;           ca.n[8]=4096;
    ca.src[9]=as3; ca.dst[9]=s3F+0;         ca.n[9]=4;
    ca.src[10]=ad3; ca.dst[10]=s3F+16;      ca.n[10]=4;
    ca.src[11]=b3;  ca.dst[11]=s3F+32;      ca.n[11]=4;

    k_setup<<<dim3(1024, 14), 256, 0, stream>>>(ca, W2, (const uint32*)W1, (const int*)ei,
                                                counts, W2T, flags);
    k_extract_hist<<<EB, 256, 0, stream>>>(ei, flags, srcA, dstA, counts);
    k_scan<<<1, 1024, 0, stream>>>(counts, offs, cursors, N_NODES);
    k_scatter<<<EB, 256, 0, stream>>>(srcA, dstA, cursors, ssort);

    /* layer 1 (gemm + dots fused); agg: 8 heads x 2500 node-groups, head = bid&7 -> XCD-affine */
    k_gemm1f<<<512, 256, 0, stream>>>(xF, W1F, wvecF+0*1024, wvecF+1*1024, bufA, alS, alD);
    k_gat_agg<<<20000, 256, 0, stream>>>(bufA, alS, alD, offs, ssort, wvecF+2*1024, bufB);

    /* layer 2 (gemm + dots fused, XCD-swizzled linear grid, 8-wave 2-phase dbuf) */
    k_gemm2<<<640, 512, 0, stream>>>(bufB, W2T, bufA, wvecF+3*1024, wvecF+4*1024, alS, alD);
    k_gat_agg<<<20000, 256, 0, stream>>>(bufA, alS, alD, offs, ssort, wvecF+5*1024, bufB);

    /* layer 3 */
    k_gemm3<<<2500, 256, 0, stream>>>(bufB, W3F, s3F, h3, al3s, al3d);
    k_gat_agg3<<<2500, 256, 0, stream>>>(h3, al3s, al3d, offs, ssort, s3F+32, flags, d_out);
}

// Round 9
// 315.471 us; speedup vs baseline: 1.0027x; 1.0027x over previous
//
#include <hip/hip_runtime.h>

typedef unsigned short ushort_t;
typedef unsigned int uint32;

#define N_NODES 10000
#define N_EDGES 160000
#define ET (N_NODES + N_EDGES)   /* 170000 edges incl self-loops */
#define MPAD 10112               /* 79 * 128 */
#define HT 1024                  /* heads * hid */
#define HEADS 8
#define NEG 0.2f
#define LOG2E 1.44269504088896f
#define EXP2(x) __builtin_amdgcn_exp2f(x)

/* ---- ws layout (bytes, 256-aligned) ---- */
#define O_FLAG     0             /* flags[0]=edge64, flags[1]=inputs_f32 */
#define O_SRC      256
#define O_DST      (O_SRC + 680192)
#define O_COUNTS   (O_DST + 680192)
#define O_OFFS     (O_COUNTS + 40192)
#define O_CURS     (O_OFFS + 40192)
#define O_SSORT    (O_CURS + 40192)
#define O_ALS      (O_SSORT + 680192)
#define O_ALD      (O_ALS + 320000)
#define O_AL3S     (O_ALD + 320000)
#define O_AL3D     (O_AL3S + 40192)
#define O_H3       (O_AL3D + 40192)
#define O_XF       (O_H3 + 160000)      /* x fp32: 140000 floats */
#define O_W1F      (O_XF + 560128)      /* 14336 floats */
#define O_AS1F     (O_W1F + 57344)      /* 6 x 1024 floats: as1,ad1,b1,as2,ad2,b2 */
#define O_W3F      (O_AS1F + 24576)     /* 4096 floats */
#define O_S3F      (O_W3F + 16384)      /* as3 @0, ad3 @+16 floats, b3 @+32 floats */
#define O_W2T      (O_S3F + 768)        /* bf16 [1024,1024] transposed */
#define O_BUFA     (O_W2T + 2097152)
#define O_BUFB     (O_BUFA + 20709376)

__device__ __forceinline__ float bf2f(ushort_t u){ return __uint_as_float(((uint32)u) << 16); }
__device__ __forceinline__ ushort_t f2bf(float f){
    uint32 x = __float_as_uint(f);
    return (ushort_t)((x + 0x7fffu + ((x >> 16) & 1u)) >> 16);
}
__device__ __forceinline__ void unpack2(uint32 u, float& lo, float& hi){
    lo = __uint_as_float(u << 16);
    hi = __uint_as_float(u & 0xffff0000u);
}

typedef __bf16 bf16x8 __attribute__((ext_vector_type(8)));
typedef float  f32x4  __attribute__((ext_vector_type(4)));

typedef const __attribute__((address_space(1))) uint32* gas1_u32;
typedef       __attribute__((address_space(3))) uint32* las3_u32;

__device__ __forceinline__ void gload_lds16(const void* g, void* l){
    __builtin_amdgcn_global_load_lds((gas1_u32)g, (las3_u32)l, 16, 0, 0);
}

/* inline dtype probes: bf16 low-element exponent field concentrates near 127;
   fp32 low 16 bits are uniform mantissa bits. */
__device__ __forceinline__ int probe_f32(const uint32* __restrict__ w){
    int cnt = 0;
    for (int i = 0; i < 256; i++){
        uint32 e = (w[i] >> 7) & 0xffu;
        cnt += (e >= 64u && e <= 160u) ? 1 : 0;
    }
    return (cnt > 200) ? 0 : 1;
}
__device__ __forceinline__ int probe_edge64(const int* __restrict__ ei){
    int nz = 0;
    for (int i = 0; i < 128; i++) nz |= ei[2*i + 1];
    return (nz == 0) ? 1 : 0;
}

/* ---------------- k_probe: compute dtype flags ONCE (hoisted out of k_setup,
   which previously ran the 256-iter probe loop in every thread) ---------------- */
__global__ __launch_bounds__(64) void k_probe(const uint32* __restrict__ w1raw,
                                              const int* __restrict__ eiraw,
                                              int* __restrict__ flags){
    if (threadIdx.x == 0) flags[1] = probe_f32(w1raw);
    if (threadIdx.x == 1) flags[0] = probe_edge64(eiraw);
}

/* ---------------- k_setup ---------------- */
struct CvtArgs {
    const void* src[12];
    float*      dst[12];
    int         n[12];
    float       scl[12];     /* per-slice scale: LOG2E for a_src/a_dst vectors */
};

__global__ __launch_bounds__(256) void k_setup(CvtArgs a, const void* __restrict__ W2,
                                               int* __restrict__ counts,
                                               ushort_t* __restrict__ W2T,
                                               const int* __restrict__ flags){
    __shared__ ushort_t tile[32][33];
    int slice = blockIdx.y;
    int tid = threadIdx.x;
    if (slice < 12){
        int n = a.n[slice];
        int base = blockIdx.x * 1024 + tid * 4;
        if (base >= n) return;
        int f32 = flags[1];
        float scl = a.scl[slice];
        const void* s = a.src[slice];
        float* d = a.dst[slice];
        #pragma unroll
        for (int j = 0; j < 4; j++){
            int i = base + j;
            if (i < n) d[i] = scl * (f32 ? ((const float*)s)[i] : bf2f(((const ushort_t*)s)[i]));
        }
    } else if (slice == 12){
        if (blockIdx.x < 10){
            int i0 = blockIdx.x * 1024 + tid * 4;
            if (i0 + 3 < N_NODES){
                *(int4*)(counts + i0) = make_int4(0,0,0,0);
            } else {
                for (int j = 0; j < 4; j++) if (i0 + j < N_NODES) counts[i0 + j] = 0;
            }
        }
    } else {
        int f32 = flags[1];
        int bx = blockIdx.x & 31, by = blockIdx.x >> 5;
        int cx = tid & 31;
        int ry = (tid >> 5) * 4;
        #pragma unroll
        for (int r = 0; r < 4; r++){
            size_t idx = (size_t)(by*32 + ry + r)*1024 + bx*32 + cx;
            tile[ry + r][cx] = f32 ? f2bf(((const float*)W2)[idx]) : ((const ushort_t*)W2)[idx];
        }
        __syncthreads();
        #pragma unroll
        for (int r = 0; r < 4; r++)
            W2T[(size_t)(bx*32 + ry + r)*1024 + by*32 + cx] = tile[cx][ry + r];
    }
}

/* ---------------- extract edges (+self-loops) as int32, fused histogram ---------------- */
__global__ __launch_bounds__(256) void k_extract_hist(const void* __restrict__ ei, const int* __restrict__ flags,
                                                      int* __restrict__ src, int* __restrict__ dst,
                                                      int* __restrict__ counts){
    int i = blockIdx.x * 256 + threadIdx.x;
    int is64 = flags[0];
    int s = -1, d = -1;
    if (i < N_EDGES){
        if (is64){
            const long long* p = (const long long*)ei;
            s = (int)p[i]; d = (int)p[N_EDGES + i];
        } else {
            const int* p = (const int*)ei;
            s = p[i]; d = p[N_EDGES + i];
        }
    } else if (i < ET){
        s = i - N_EDGES; d = s;
    }
    if (d >= 0){
        src[i] = s; dst[i] = d;
        atomicAdd(&counts[d], 1);
    }
}

/* single-block exclusive scan over N_NODES counts -> offs + cursors */
__global__ __launch_bounds__(1024) void k_scan(const int* __restrict__ counts, int* __restrict__ offs,
                                               int* __restrict__ cursors, int n){
    __shared__ int wsum[16];
    __shared__ int running_s;
    int tid = threadIdx.x;
    int lane = tid & 63, wid = tid >> 6;
    if (tid == 0) running_s = 0;
    __syncthreads();
    for (int base = 0; base < n; base += 1024){
        int i = base + tid;
        int v = (i < n) ? counts[i] : 0;
        int x = v;
        #pragma unroll
        for (int d = 1; d < 64; d <<= 1){
            int t = __shfl_up(x, d, 64);
            if (lane >= d) x += t;
        }
        if (lane == 63) wsum[wid] = x;
        __syncthreads();
        if (wid == 0 && lane < 16){
            int w = wsum[lane];
            #pragma unroll
            for (int d = 1; d < 16; d <<= 1){
                int t = __shfl_up(w, d, 64);
                if (lane >= d) w += t;
            }
            wsum[lane] = w;
        }
        __syncthreads();
        int wprefix = (wid == 0) ? 0 : wsum[wid - 1];
        int run = running_s;
        int excl = run + wprefix + (x - v);
        if (i < n){ offs[i] = excl; cursors[i] = excl; }
        __syncthreads();
        if (tid == 0) running_s = run + wsum[15];
        __syncthreads();
    }
    if (tid == 0) offs[n] = running_s;
}

/* scatter stores PRE-SCALED src*8: gat_agg's alS index = sp+head and H offset
   = sp*128 shorts, removing a shift from both hot address chains. gat_agg3
   recovers s via sp>>3 (1 op in a small kernel). */
__global__ __launch_bounds__(256) void k_scatter(const int* __restrict__ src, const int* __restrict__ dst,
                                                 int* __restrict__ cursors, int* __restrict__ ssort){
    int i = blockIdx.x * 256 + threadIdx.x;
    if (i < ET){
        int pos = atomicAdd(&cursors[dst[i]], 1);
        ssort[pos] = src[i] * 8;
    }
}

/* ---------------- layer-1 GEMM fused with attention dots ---------------- */
__global__ __launch_bounds__(256) void k_gemm1f(const float* __restrict__ x, const float* __restrict__ W1,
                                                const float* __restrict__ a_src, const float* __restrict__ a_dst,
                                                ushort_t* __restrict__ h1,
                                                float* __restrict__ alS, float* __restrict__ alD){
    __shared__ float w1s[14 * HT];
    int tid = threadIdx.x;
    for (int i = tid * 4; i < 14 * HT; i += 1024)
        *(float4*)(w1s + i) = *(const float4*)(W1 + i);
    int c0 = tid * 4;
    float4 sv = *(const float4*)(a_src + c0);
    float4 dv = *(const float4*)(a_dst + c0);
    int head = tid >> 5, l32 = tid & 31;
    __syncthreads();
    for (int n = blockIdx.x; n < N_NODES; n += gridDim.x){
        float a0=0.f, a1=0.f, a2=0.f, a3=0.f;
        #pragma unroll
        for (int k = 0; k < 14; k++){
            float xv = x[n*14 + k];
            float4 w = *(const float4*)(w1s + k*HT + c0);
            a0 += xv*w.x; a1 += xv*w.y; a2 += xv*w.z; a3 += xv*w.w;
        }
        uint2 o;
        o.x = (uint32)f2bf(a0) | ((uint32)f2bf(a1) << 16);
        o.y = (uint32)f2bf(a2) | ((uint32)f2bf(a3) << 16);
        *(uint2*)(h1 + (size_t)n*HT + c0) = o;
        float h0,h1v,h2,h3v;
        unpack2(o.x, h0, h1v); unpack2(o.y, h2, h3v);
        float s = h0*sv.x + h1v*sv.y + h2*sv.z + h3v*sv.w;
        float d = h0*dv.x + h1v*dv.y + h2*dv.z + h3v*dv.w;
        #pragma unroll
        for (int of = 16; of; of >>= 1){ s += __shfl_xor(s, of, 32); d += __shfl_xor(d, of, 32); }
        if (l32 == 0){ alS[n*HEADS + head] = s; alD[n*HEADS + head] = d; }
    }
}

/* ---------------- fused segment-softmax + aggregate + bias + relu (v5.3) ----------------
   Head-partitioned, XCD-affine gather (R4/R5): block b -> head = b&7; per-XCD
   H slice 2.56 MB (FETCH 146->15.7 MB, proven). VALU-bound (92%), so v5.3 cuts
   dead instructions: srcs pre-scaled (s*8) removes a shift from both address
   chains; a_src/a_dst pre-scaled by log2e upstream (leaky is positively
   homogeneous -> exact) so every exp is a bare v_exp_f32 via exp2. */
__global__ __launch_bounds__(256) void k_gat_agg(const ushort_t* __restrict__ H, const float* __restrict__ alS,
                                                 const float* __restrict__ alD, const int* __restrict__ offs,
                                                 const int* __restrict__ srcs, const float* __restrict__ bias,
                                                 ushort_t* __restrict__ out){
    int tid = threadIdx.x;
    int wv = tid >> 6, lane = tid & 63;
    int head = blockIdx.x & 7;
    int n = (blockIdx.x >> 3) * 4 + wv;
    if (n >= N_NODES) return;
    int beg = offs[n], end = offs[n+1];
    int g = lane >> 4;           /* edge slot 0..3 */
    int q = lane & 15;           /* 8-channel sub-block within head */
    float ad = alD[n*HEADS + head];
    const ushort_t* Hh = H + head*128 + q*8;
    const float NINF = -__int_as_float(0x7f800000);

    float m = -1e30f, z = 0.f;
    float c0=0.f,c1=0.f,c2=0.f,c3=0.f,c4=0.f,c5=0.f,c6=0.f,c7=0.f;
    for (int c = beg; c < end; c += 64){
        int cn = min(64, end - c);
        int sreg = (lane < cn) ? srcs[c + lane] : 0;
        int j = 0;
        /* 8-edge body: e1 = j+4+g <= j+7 < cn, so no masking needed */
        for (; j + 8 <= cn; j += 8){
            int s0 = __shfl(sreg, j + g, 64);       /* = src*8 */
            int s1 = __shfl(sreg, j + 4 + g, 64);
            uint4 u0 = *(const uint4*)(Hh + (size_t)s0*128);
            uint4 u1 = *(const uint4*)(Hh + (size_t)s1*128);
            float v0 = alS[s0 + head] + ad; v0 = v0 > 0.f ? v0 : NEG*v0;
            float v1 = alS[s1 + head] + ad; v1 = v1 > 0.f ? v1 : NEG*v1;
            float vm = fmaxf(v0, v1);
            if (vm > m){
                float sc = EXP2(m - vm);
                z *= sc;
                c0*=sc; c1*=sc; c2*=sc; c3*=sc;
                c4*=sc; c5*=sc; c6*=sc; c7*=sc;
                m = vm;
            }
            float w0 = EXP2(v0 - m);
            float w1 = EXP2(v1 - m);
            z += (w0 + w1);
            float f0,f1,f2,f3,f4,f5,f6,f7;
            float g0,g1,g2,g3,g4,g5,g6,g7;
            unpack2(u0.x,f0,f1); unpack2(u0.y,f2,f3); unpack2(u0.z,f4,f5); unpack2(u0.w,f6,f7);
            unpack2(u1.x,g0,g1); unpack2(u1.y,g2,g3); unpack2(u1.z,g4,g5); unpack2(u1.w,g6,g7);
            c0 = fmaf(w0,f0, fmaf(w1,g0, c0));
            c1 = fmaf(w0,f1, fmaf(w1,g1, c1));
            c2 = fmaf(w0,f2, fmaf(w1,g2, c2));
            c3 = fmaf(w0,f3, fmaf(w1,g3, c3));
            c4 = fmaf(w0,f4, fmaf(w1,g4, c4));
            c5 = fmaf(w0,f5, fmaf(w1,g5, c5));
            c6 = fmaf(w0,f6, fmaf(w1,g6, c6));
            c7 = fmaf(w0,f7, fmaf(w1,g7, c7));
        }
        /* masked tail, 4 edges at a time */
        for (; j < cn; j += 4){
            int e = j + g;
            int s0 = __shfl(sreg, e, 64);
            uint4 u0 = *(const uint4*)(Hh + (size_t)s0*128);
            float v0 = alS[s0 + head] + ad; v0 = v0 > 0.f ? v0 : NEG*v0;
            v0 = (e < cn) ? v0 : NINF;          /* exp2(NINF - finite) == 0 */
            if (v0 > m){
                float sc = EXP2(m - v0);
                z *= sc;
                c0*=sc; c1*=sc; c2*=sc; c3*=sc;
                c4*=sc; c5*=sc; c6*=sc; c7*=sc;
                m = v0;
            }
            float w0 = EXP2(v0 - m);
            z += w0;
            float f0,f1,f2,f3,f4,f5,f6,f7;
            unpack2(u0.x,f0,f1); unpack2(u0.y,f2,f3); unpack2(u0.z,f4,f5); unpack2(u0.w,f6,f7);
            c0 = fmaf(w0,f0, c0); c1 = fmaf(w0,f1, c1);
            c2 = fmaf(w0,f2, c2); c3 = fmaf(w0,f3, c3);
            c4 = fmaf(w0,f4, c4); c5 = fmaf(w0,f5, c5);
            c6 = fmaf(w0,f6, c6); c7 = fmaf(w0,f7, c7);
        }
    }
    /* merge (m,z,c[8]) across the 4 edge-groups: xor 16 then 32 */
    #pragma unroll
    for (int off = 16; off < 64; off <<= 1){
        float m2 = __shfl_xor(m, off, 64);
        float z2 = __shfl_xor(z, off, 64);
        float d0 = __shfl_xor(c0, off, 64);
        float d1 = __shfl_xor(c1, off, 64);
        float d2 = __shfl_xor(c2, off, 64);
        float d3 = __shfl_xor(c3, off, 64);
        float d4 = __shfl_xor(c4, off, 64);
        float d5 = __shfl_xor(c5, off, 64);
        float d6 = __shfl_xor(c6, off, 64);
        float d7 = __shfl_xor(c7, off, 64);
        float nm = fmaxf(m, m2);
        float a = EXP2(m - nm), b = EXP2(m2 - nm);
        z = z*a + z2*b;
        c0 = c0*a + d0*b; c1 = c1*a + d1*b;
        c2 = c2*a + d2*b; c3 = c3*a + d3*b;
        c4 = c4*a + d4*b; c5 = c5*a + d5*b;
        c6 = c6*a + d6*b; c7 = c7*a + d7*b;
        m = nm;
    }
    if (g == 0){
        float inv = 1.f / (z + 1e-16f);
        int ch0 = head*128 + q*8;
        float4 b0 = *(const float4*)(bias + ch0);
        float4 b1 = *(const float4*)(bias + ch0 + 4);
        c0 = fmaxf(c0*inv+b0.x, 0.f); c1 = fmaxf(c1*inv+b0.y, 0.f);
        c2 = fmaxf(c2*inv+b0.z, 0.f); c3 = fmaxf(c3*inv+b0.w, 0.f);
        c4 = fmaxf(c4*inv+b1.x, 0.f); c5 = fmaxf(c5*inv+b1.y, 0.f);
        c6 = fmaxf(c6*inv+b1.z, 0.f); c7 = fmaxf(c7*inv+b1.w, 0.f);
        uint4 o;
        o.x = (uint32)f2bf(c0) | ((uint32)f2bf(c1) << 16);
        o.y = (uint32)f2bf(c2) | ((uint32)f2bf(c3) << 16);
        o.z = (uint32)f2bf(c4) | ((uint32)f2bf(c5) << 16);
        o.w = (uint32)f2bf(c6) | ((uint32)f2bf(c7) << 16);
        *(uint4*)(out + (size_t)n*HT + ch0) = o;
    }
}

/* ---------------- layer-2 GEMM: bf16 MFMA, fused attention dots (v4) ----------------
   8 waves (512 threads), wave owns 64x32 of the 128x128 tile (R5: doubled
   resident waves at identical LDS). BK=64 2-phase double-buffered pipeline;
   attention-dot epilogue combines 4 wn-waves via LDS partials. */
__global__ __launch_bounds__(512) void k_gemm2(const ushort_t* __restrict__ A, const ushort_t* __restrict__ BT,
                                               ushort_t* __restrict__ C,
                                               const float* __restrict__ aS, const float* __restrict__ aD,
                                               float* __restrict__ alS, float* __restrict__ alD){
    __shared__ ushort_t lbuf[2][2][128*64];       /* [buf][0=A,1=B][row*64+e] : 64 KiB */
    float (*reds)[3][64][2] = (float (*)[3][64][2])lbuf; /* [wm6][widx][rl][s/d], aliased after K-loop */
    int L = blockIdx.x;
    int xcd = L & 7;
    int wi  = L >> 3;
    int bm  = xcd * 10 + (wi >> 3);
    int bn  = wi & 7;
    if (bm >= 79) return;
    int tid = threadIdx.x;
    int lane = tid & 63;
    int wave = tid >> 6;                  /* 0..7 */
    int wm  = (wave & 1) * 64;            /* row half */
    int wn32 = (wave >> 1) * 32;          /* 32-col strip */
    int lm = lane & 15, kg = lane >> 4;
    int c0 = (kg ^ (lm & 7)) * 8;    /* phys elem offset of ksub0 fragment; ksub1 = c0^32 */
    f32x4 acc[4][2];
    #pragma unroll
    for (int i = 0; i < 4; i++)
        #pragma unroll
        for (int j = 0; j < 2; j++) acc[i][j] = (f32x4)0.0f;

    const int K = 1024;
    int rowA0 = bm * 128, rowB0 = bn * 128;

    auto stage = [&](int buf, int k0){
        #pragma unroll
        for (int it = 0; it < 2; ++it){
            int s = tid + it*512;           /* chunk id in [0,1024): row = s>>3, phys chunk = s&7 */
            int r = s >> 3;
            int q = (s & 7) ^ (r & 7);      /* logical chunk living at this phys slot */
            gload_lds16(A  + (size_t)(rowA0 + r)*K + k0 + q*8, &lbuf[buf][0][s*8]);
            gload_lds16(BT + (size_t)(rowB0 + r)*K + k0 + q*8, &lbuf[buf][1][s*8]);
        }
    };

    stage(0, 0);
    asm volatile("s_waitcnt vmcnt(0)" ::: "memory");
    __syncthreads();
    int cur = 0;
    for (int k0 = 0; k0 < K; k0 += 64){
        if (k0 + 64 < K) stage(cur ^ 1, k0 + 64);   /* prefetch next tile first */
        bf16x8 a0[4], a1[4], b0[2], b1[2];
        #pragma unroll
        for (int mt = 0; mt < 4; mt++){
            const ushort_t* base = &lbuf[cur][0][(wm + mt*16 + lm)*64];
            a0[mt] = *(const bf16x8*)(base + c0);
            a1[mt] = *(const bf16x8*)(base + (c0 ^ 32));
        }
        #pragma unroll
        for (int nt = 0; nt < 2; nt++){
            const ushort_t* base = &lbuf[cur][1][(wn32 + nt*16 + lm)*64];
            b0[nt] = *(const bf16x8*)(base + c0);
            b1[nt] = *(const bf16x8*)(base + (c0 ^ 32));
        }
        #pragma unroll
        for (int mt = 0; mt < 4; mt++)
            #pragma unroll
            for (int nt = 0; nt < 2; nt++)
                acc[mt][nt] = __builtin_amdgcn_mfma_f32_16x16x32_bf16(a0[mt], b0[nt], acc[mt][nt], 0, 0, 0);
        #pragma unroll
        for (int mt = 0; mt < 4; mt++)
            #pragma unroll
            for (int nt = 0; nt < 2; nt++)
                acc[mt][nt] = __builtin_amdgcn_mfma_f32_16x16x32_bf16(a1[mt], b1[nt], acc[mt][nt], 0, 0, 0);
        asm volatile("s_waitcnt vmcnt(0)" ::: "memory");
        __syncthreads();
        cur ^= 1;
    }
    #pragma unroll
    for (int mt = 0; mt < 4; mt++){
        int row_base = bm*128 + wm + mt*16 + kg*4;
        #pragma unroll
        for (int nt = 0; nt < 2; nt++){
            int col = bn*128 + wn32 + nt*16 + lm;
            #pragma unroll
            for (int r = 0; r < 4; r++){
                int row = row_base + r;
                if (row < N_NODES) C[(size_t)row*HT + col] = f2bf(acc[mt][nt][r]);
            }
        }
    }
    /* fused attention-dot epilogue for head bn: wave partial over its 32 cols,
       combine 4 wn-waves through LDS partials */
    float as_l[2], ad_l[2];
    #pragma unroll
    for (int nt = 0; nt < 2; nt++){
        as_l[nt] = aS[bn*128 + wn32 + nt*16 + lm];
        ad_l[nt] = aD[bn*128 + wn32 + nt*16 + lm];
    }
    float psA[4][4], pdA[4][4];
    #pragma unroll
    for (int mt = 0; mt < 4; mt++){
        #pragma unroll
        for (int r = 0; r < 4; r++){
            float ps = acc[mt][0][r]*as_l[0] + acc[mt][1][r]*as_l[1];
            float pd = acc[mt][0][r]*ad_l[0] + acc[mt][1][r]*ad_l[1];
            #pragma unroll
            for (int o = 1; o < 16; o <<= 1){ ps += __shfl_xor(ps, o, 64); pd += __shfl_xor(pd, o, 64); }
            psA[mt][r] = ps; pdA[mt][r] = pd;
            if (wn32 != 0 && lm == 0){
                int rl = mt*16 + kg*4 + r;
                reds[wm >> 6][(wn32 >> 5) - 1][rl][0] = ps;
                reds[wm >> 6][(wn32 >> 5) - 1][rl][1] = pd;
            }
        }
    }
    __syncthreads();
    if (wn32 == 0 && lm == 0){
        #pragma unroll
        for (int mt = 0; mt < 4; mt++){
            #pragma unroll
            for (int r = 0; r < 4; r++){
                int rl = mt*16 + kg*4 + r;
                int row = bm*128 + wm + rl;
                if (row < N_NODES){
                    alS[row*HEADS + bn] = psA[mt][r] + reds[wm >> 6][0][rl][0]
                                        + reds[wm >> 6][1][rl][0] + reds[wm >> 6][2][rl][0];
                    alD[row*HEADS + bn] = pdA[mt][r] + reds[wm >> 6][0][rl][1]
                                        + reds[wm >> 6][1][rl][1] + reds[wm >> 6][2][rl][1];
                }
            }
        }
    }
}

/* ---------------- layer-3 GEMM: wave-per-node, W3 in registers ---------------- */
__global__ __launch_bounds__(256) void k_gemm3(const ushort_t* __restrict__ A, const float* __restrict__ W3,
                                               const float* __restrict__ s3,
                                               float* __restrict__ h3, float* __restrict__ al3s, float* __restrict__ al3d){
    int tid = threadIdx.x;
    int lane = tid & 63, wave = tid >> 6;
    int n = blockIdx.x * 4 + wave;
    if (n >= N_NODES) return;
    float4 w3r[16];
    #pragma unroll
    for (int j = 0; j < 16; j++) w3r[j] = ((const float4*)W3)[lane*16 + j];
    const uint4* ap = (const uint4*)(A + (size_t)n*HT + lane*16);
    uint4 u0 = ap[0], u1 = ap[1];
    uint32 uu[8] = {u0.x,u0.y,u0.z,u0.w,u1.x,u1.y,u1.z,u1.w};
    float acc0=0.f, acc1=0.f, acc2=0.f, acc3=0.f;
    #pragma unroll
    for (int p = 0; p < 8; p++){
        float lo, hi;
        unpack2(uu[p], lo, hi);
        float4 wl = w3r[p*2], wh = w3r[p*2+1];
        acc0 += lo*wl.x + hi*wh.x;
        acc1 += lo*wl.y + hi*wh.y;
        acc2 += lo*wl.z + hi*wh.z;
        acc3 += lo*wl.w + hi*wh.w;
    }
    #pragma unroll
    for (int o = 32; o; o >>= 1){
        acc0 += __shfl_xor(acc0, o, 64); acc1 += __shfl_xor(acc1, o, 64);
        acc2 += __shfl_xor(acc2, o, 64); acc3 += __shfl_xor(acc3, o, 64);
    }
    if (lane == 0){
        *(float4*)(h3 + n*4) = make_float4(acc0, acc1, acc2, acc3);
        al3s[n] = acc0*s3[0] + acc1*s3[1] + acc2*s3[2] + acc3*s3[3];
        al3d[n] = acc0*s3[16] + acc1*s3[17] + acc2*s3[18] + acc3*s3[19];
    }
}

/* ---------------- layer-3 attention aggregate: wave-per-node ----------------
   srcs now pre-scaled (s*8): al3s index = sp>>3, h3 float index = sp>>1.
   al3s/al3d pre-scaled by log2e (as3/ad3 scaled at setup) -> exp2. */
__global__ __launch_bounds__(256) void k_gat_agg3(const float* __restrict__ h3, const float* __restrict__ al3s,
                                                  const float* __restrict__ al3d, const int* __restrict__ offs,
                                                  const int* __restrict__ srcs, const float* __restrict__ b3,
                                                  const int* __restrict__ flags, void* __restrict__ out){
    int tid = threadIdx.x;
    int l = tid & 63, wave = tid >> 6;
    int n = blockIdx.x * 4 + wave;
    if (n >= N_NODES) return;
    int beg = offs[n], end = offs[n+1];
    float ad = al3d[n];
    float m = -1e30f;
    for (int e = beg + l; e < end; e += 64){
        float v = al3s[srcs[e] >> 3] + ad; v = v > 0.f ? v : NEG*v;
        m = fmaxf(m, v);
    }
    #pragma unroll
    for (int o = 32; o; o >>= 1) m = fmaxf(m, __shfl_xor(m, o, 64));
    float z = 0.f;
    for (int e = beg + l; e < end; e += 64){
        float v = al3s[srcs[e] >> 3] + ad; v = v > 0.f ? v : NEG*v;
        z += EXP2(v - m);
    }
    #pragma unroll
    for (int o = 32; o; o >>= 1) z += __shfl_xor(z, o, 64);
    float inv = 1.f / (z + 1e-16f);
    float a0=0.f, a1=0.f, a2=0.f, a3=0.f;
    for (int e = beg + l; e < end; e += 64){
        int sp = srcs[e];
        float v = al3s[sp >> 3] + ad; v = v > 0.f ? v : NEG*v;
        float w = EXP2(v - m) * inv;
        float4 hv = *(const float4*)(h3 + (sp >> 1));
        a0 += w*hv.x; a1 += w*hv.y; a2 += w*hv.z; a3 += w*hv.w;
    }
    #pragma unroll
    for (int o = 32; o; o >>= 1){
        a0 += __shfl_xor(a0, o, 64); a1 += __shfl_xor(a1, o, 64);
        a2 += __shfl_xor(a2, o, 64); a3 += __shfl_xor(a3, o, 64);
    }
    if (l == 0){
        float r0 = fmaxf(a0 + b3[0], 0.f);
        float r1 = fmaxf(a1 + b3[1], 0.f);
        float r2 = fmaxf(a2 + b3[2], 0.f);
        float r3 = fmaxf(a3 + b3[3], 0.f);
        if (flags[1]){
            float* o4 = (float*)out;
            o4[n*4+0]=r0; o4[n*4+1]=r1; o4[n*4+2]=r2; o4[n*4+3]=r3;
        } else {
            ushort_t* o2 = (ushort_t*)out;
            o2[n*4+0]=f2bf(r0); o2[n*4+1]=f2bf(r1); o2[n*4+2]=f2bf(r2); o2[n*4+3]=f2bf(r3);
        }
    }
}

extern "C" void kernel_launch(void* const* d_in, const int* in_sizes, int n_in,
                              void* d_out, int out_size, void* d_ws, size_t ws_size,
                              hipStream_t stream){
    const void* x   = d_in[0];
    const void* ei  = d_in[1];
    const void* W1  = d_in[2];
    const void* as1 = d_in[3];
    const void* ad1 = d_in[4];
    const void* b1  = d_in[5];
    const void* W2  = d_in[6];
    const void* as2 = d_in[7];
    const void* ad2 = d_in[8];
    const void* b2  = d_in[9];
    const void* W3  = d_in[10];
    const void* as3 = d_in[11];
    const void* ad3 = d_in[12];
    const void* b3  = d_in[13];

    char* ws = (char*)d_ws;
    int* flags     = (int*)(ws + O_FLAG);
    int* srcA      = (int*)(ws + O_SRC);
    int* dstA      = (int*)(ws + O_DST);
    int* counts    = (int*)(ws + O_COUNTS);
    int* offs      = (int*)(ws + O_OFFS);
    int* cursors   = (int*)(ws + O_CURS);
    int* ssort     = (int*)(ws + O_SSORT);
    float* alS     = (float*)(ws + O_ALS);
    float* alD     = (float*)(ws + O_ALD);
    float* al3s    = (float*)(ws + O_AL3S);
    float* al3d    = (float*)(ws + O_AL3D);
    float* h3      = (float*)(ws + O_H3);
    float* xF      = (float*)(ws + O_XF);
    float* W1F     = (float*)(ws + O_W1F);
    float* wvecF   = (float*)(ws + O_AS1F);
    float* W3F     = (float*)(ws + O_W3F);
    float* s3F     = (float*)(ws + O_S3F);
    ushort_t* W2T  = (ushort_t*)(ws + O_W2T);
    ushort_t* bufA = (ushort_t*)(ws + O_BUFA);
    ushort_t* bufB = (ushort_t*)(ws + O_BUFB);

    const int EB = (ET + 255) / 256;

    CvtArgs ca;
    ca.src[0]=x;   ca.dst[0]=xF;            ca.n[0]=140000;  ca.scl[0]=1.0f;
    ca.src[1]=W1;  ca.dst[1]=W1F;           ca.n[1]=14336;   ca.scl[1]=1.0f;
    ca.src[2]=as1; ca.dst[2]=wvecF+0*1024;  ca.n[2]=1024;    ca.scl[2]=LOG2E;
    ca.src[3]=ad1; ca.dst[3]=wvecF+1*1024;  ca.n[3]=1024;    ca.scl[3]=LOG2E;
    ca.src[4]=b1;  ca.dst[4]=wvecF+2*1024;  ca.n[4]=1024;    ca.scl[4]=1.0f;
    ca.src[5]=as2; ca.dst[5]=wvecF+3*1024;  ca.n[5]=1024;    ca.scl[5]=LOG2E;
    ca.src[6]=ad2; ca.dst[6]=wvecF+4*1024;  ca.n[6]=1024;    ca.scl[6]=LOG2E;
    ca.src[7]=b2;  ca.dst[7]=wvecF+5*1024;  ca.n[7]=1024;    ca.scl[7]=1.0f;
    ca.src[8]=W3;  ca.dst[8]=W3F;           ca.n[8]=4096;    ca.scl[8]=1.0f;
    ca.src[9]=as3; ca.dst[9]=s3F+0;         ca.n[9]=4;       ca.scl[9]=LOG2E;
    ca.src[10]=ad3; ca.dst[10]=s3F+16;      ca.n[10]=4;      ca.scl[10]=LOG2E;
    ca.src[11]=b3;  ca.dst[11]=s3F+32;      ca.n[11]=4;      ca.scl[11]=1.0f;

    k_probe<<<1, 64, 0, stream>>>((const uint32*)W1, (const int*)ei, flags);
    k_setup<<<dim3(1024, 14), 256, 0, stream>>>(ca, W2, counts, W2T, flags);
    k_extract_hist<<<EB, 256, 0, stream>>>(ei, flags, srcA, dstA, counts);
    k_scan<<<1, 1024, 0, stream>>>(counts, offs, cursors, N_NODES);
    k_scatter<<<EB, 256, 0, stream>>>(srcA, dstA, cursors, ssort);

    /* layer 1 (gemm + dots fused); agg: 8 heads x 2500 node-groups, head = bid&7 -> XCD-affine */
    k_gemm1f<<<512, 256, 0, stream>>>(xF, W1F, wvecF+0*1024, wvecF+1*1024, bufA, alS, alD);
    k_gat_agg<<<20000, 256, 0, stream>>>(bufA, alS, alD, offs, ssort, wvecF+2*1024, bufB);

    /* layer 2 (gemm + dots fused, XCD-swizzled linear grid, 8-wave 2-phase dbuf) */
    k_gemm2<<<640, 512, 0, stream>>>(bufB, W2T, bufA, wvecF+3*1024, wvecF+4*1024, alS, alD);
    k_gat_agg<<<20000, 256, 0, stream>>>(bufA, alS, alD, offs, ssort, wvecF+5*1024, bufB);

    /* layer 3 */
    k_gemm3<<<2500, 256, 0, stream>>>(bufB, W3F, s3F, h3, al3s, al3d);
    k_gat_agg3<<<2500, 256, 0, stream>>>(h3, al3s, al3d, offs, ssort, s3F+32, flags, d_out);
}

// Round 10
// 304.954 us; speedup vs baseline: 1.0373x; 1.0345x over previous
//
#include <hip/hip_runtime.h>

typedef unsigned short ushort_t;
typedef unsigned int uint32;

#define N_NODES 10000
#define N_EDGES 160000
#define ET (N_NODES + N_EDGES)   /* 170000 edges incl self-loops */
#define MPAD 10112               /* 79 * 128 */
#define HT 1024                  /* heads * hid */
#define HEADS 8
#define NEG 0.2f
#define LOG2E 1.44269504088896f
#define EXP2(x) __builtin_amdgcn_exp2f(x)

/* ---- ws layout (bytes, 256-aligned) ---- */
#define O_FLAG     0             /* flags[0]=edge64, flags[1]=inputs_f32 */
#define O_SRC      256
#define O_DST      (O_SRC + 680192)
#define O_COUNTS   (O_DST + 680192)
#define O_OFFS     (O_COUNTS + 40192)
#define O_CURS     (O_OFFS + 40192)
#define O_SSORT    (O_CURS + 40192)
#define O_ALS      (O_SSORT + 680192)
#define O_ALD      (O_ALS + 320000)
#define O_AL3S     (O_ALD + 320000)
#define O_AL3D     (O_AL3S + 40192)
#define O_H3       (O_AL3D + 40192)
#define O_XF       (O_H3 + 160000)      /* x fp32: 140000 floats */
#define O_W1F      (O_XF + 560128)      /* 14336 floats */
#define O_AS1F     (O_W1F + 57344)      /* 6 x 1024 floats: as1,ad1,b1,as2,ad2,b2 */
#define O_W3F      (O_AS1F + 24576)     /* 4096 floats */
#define O_S3F      (O_W3F + 16384)      /* as3 @0, ad3 @+16 floats, b3 @+32 floats */
#define O_W2T      (O_S3F + 768)        /* bf16 [1024,1024] transposed */
#define O_BUFA     (O_W2T + 2097152)
#define O_BUFB     (O_BUFA + 20709376)

__device__ __forceinline__ float bf2f(ushort_t u){ return __uint_as_float(((uint32)u) << 16); }
__device__ __forceinline__ ushort_t f2bf(float f){
    uint32 x = __float_as_uint(f);
    return (ushort_t)((x + 0x7fffu + ((x >> 16) & 1u)) >> 16);
}
__device__ __forceinline__ void unpack2(uint32 u, float& lo, float& hi){
    lo = __uint_as_float(u << 16);
    hi = __uint_as_float(u & 0xffff0000u);
}

typedef __bf16 bf16x8 __attribute__((ext_vector_type(8)));
typedef float  f32x4  __attribute__((ext_vector_type(4)));

typedef const __attribute__((address_space(1))) uint32* gas1_u32;
typedef       __attribute__((address_space(3))) uint32* las3_u32;

__device__ __forceinline__ void gload_lds16(const void* g, void* l){
    __builtin_amdgcn_global_load_lds((gas1_u32)g, (las3_u32)l, 16, 0, 0);
}

/* inline dtype probes: bf16 low-element exponent field concentrates near 127;
   fp32 low 16 bits are uniform mantissa bits. */
__device__ __forceinline__ int probe_f32(const uint32* __restrict__ w){
    int cnt = 0;
    for (int i = 0; i < 256; i++){
        uint32 e = (w[i] >> 7) & 0xffu;
        cnt += (e >= 64u && e <= 160u) ? 1 : 0;
    }
    return (cnt > 200) ? 0 : 1;
}
__device__ __forceinline__ int probe_edge64(const int* __restrict__ ei){
    int nz = 0;
    for (int i = 0; i < 128; i++) nz |= ei[2*i + 1];
    return (nz == 0) ? 1 : 0;
}

/* ---------------- k_probe: compute dtype flags ONCE ---------------- */
__global__ __launch_bounds__(64) void k_probe(const uint32* __restrict__ w1raw,
                                              const int* __restrict__ eiraw,
                                              int* __restrict__ flags){
    if (threadIdx.x == 0) flags[1] = probe_f32(w1raw);
    if (threadIdx.x == 1) flags[0] = probe_edge64(eiraw);
}

/* ---------------- k_setup ---------------- */
struct CvtArgs {
    const void* src[12];
    float*      dst[12];
    int         n[12];
    float       scl[12];     /* per-slice scale: LOG2E for a_src/a_dst vectors */
};

__global__ __launch_bounds__(256) void k_setup(CvtArgs a, const void* __restrict__ W2,
                                               int* __restrict__ counts,
                                               ushort_t* __restrict__ W2T,
                                               const int* __restrict__ flags){
    __shared__ ushort_t tile[32][33];
    int slice = blockIdx.y;
    int tid = threadIdx.x;
    if (slice < 12){
        int n = a.n[slice];
        int base = blockIdx.x * 1024 + tid * 4;
        if (base >= n) return;
        int f32 = flags[1];
        float scl = a.scl[slice];
        const void* s = a.src[slice];
        float* d = a.dst[slice];
        #pragma unroll
        for (int j = 0; j < 4; j++){
            int i = base + j;
            if (i < n) d[i] = scl * (f32 ? ((const float*)s)[i] : bf2f(((const ushort_t*)s)[i]));
        }
    } else if (slice == 12){
        if (blockIdx.x < 10){
            int i0 = blockIdx.x * 1024 + tid * 4;
            if (i0 + 3 < N_NODES){
                *(int4*)(counts + i0) = make_int4(0,0,0,0);
            } else {
                for (int j = 0; j < 4; j++) if (i0 + j < N_NODES) counts[i0 + j] = 0;
            }
        }
    } else {
        int f32 = flags[1];
        int bx = blockIdx.x & 31, by = blockIdx.x >> 5;
        int cx = tid & 31;
        int ry = (tid >> 5) * 4;
        #pragma unroll
        for (int r = 0; r < 4; r++){
            size_t idx = (size_t)(by*32 + ry + r)*1024 + bx*32 + cx;
            tile[ry + r][cx] = f32 ? f2bf(((const float*)W2)[idx]) : ((const ushort_t*)W2)[idx];
        }
        __syncthreads();
        #pragma unroll
        for (int r = 0; r < 4; r++)
            W2T[(size_t)(bx*32 + ry + r)*1024 + by*32 + cx] = tile[cx][ry + r];
    }
}

/* ---------------- extract edges (+self-loops) as int32, fused histogram ---------------- */
__global__ __launch_bounds__(256) void k_extract_hist(const void* __restrict__ ei, const int* __restrict__ flags,
                                                      int* __restrict__ src, int* __restrict__ dst,
                                                      int* __restrict__ counts){
    int i = blockIdx.x * 256 + threadIdx.x;
    int is64 = flags[0];
    int s = -1, d = -1;
    if (i < N_EDGES){
        if (is64){
            const long long* p = (const long long*)ei;
            s = (int)p[i]; d = (int)p[N_EDGES + i];
        } else {
            const int* p = (const int*)ei;
            s = p[i]; d = p[N_EDGES + i];
        }
    } else if (i < ET){
        s = i - N_EDGES; d = s;
    }
    if (d >= 0){
        src[i] = s; dst[i] = d;
        atomicAdd(&counts[d], 1);
    }
}

/* single-block exclusive scan over N_NODES counts -> offs + cursors */
__global__ __launch_bounds__(1024) void k_scan(const int* __restrict__ counts, int* __restrict__ offs,
                                               int* __restrict__ cursors, int n){
    __shared__ int wsum[16];
    __shared__ int running_s;
    int tid = threadIdx.x;
    int lane = tid & 63, wid = tid >> 6;
    if (tid == 0) running_s = 0;
    __syncthreads();
    for (int base = 0; base < n; base += 1024){
        int i = base + tid;
        int v = (i < n) ? counts[i] : 0;
        int x = v;
        #pragma unroll
        for (int d = 1; d < 64; d <<= 1){
            int t = __shfl_up(x, d, 64);
            if (lane >= d) x += t;
        }
        if (lane == 63) wsum[wid] = x;
        __syncthreads();
        if (wid == 0 && lane < 16){
            int w = wsum[lane];
            #pragma unroll
            for (int d = 1; d < 16; d <<= 1){
                int t = __shfl_up(w, d, 64);
                if (lane >= d) w += t;
            }
            wsum[lane] = w;
        }
        __syncthreads();
        int wprefix = (wid == 0) ? 0 : wsum[wid - 1];
        int run = running_s;
        int excl = run + wprefix + (x - v);
        if (i < n){ offs[i] = excl; cursors[i] = excl; }
        __syncthreads();
        if (tid == 0) running_s = run + wsum[15];
        __syncthreads();
    }
    if (tid == 0) offs[n] = running_s;
}

/* scatter stores PRE-SCALED src*8 (R8): gat_agg's alS index = sp+head and H
   offset = sp*128 shorts; gat_agg3 recovers s via sp>>3. */
__global__ __launch_bounds__(256) void k_scatter(const int* __restrict__ src, const int* __restrict__ dst,
                                                 int* __restrict__ cursors, int* __restrict__ ssort){
    int i = blockIdx.x * 256 + threadIdx.x;
    if (i < ET){
        int pos = atomicAdd(&cursors[dst[i]], 1);
        ssort[pos] = src[i] * 8;
    }
}

/* ---------------- layer-1 GEMM fused with attention dots (v2) ----------------
   v2: W1 held in REGISTERS (14 x float4 = 56 VGPR) instead of LDS. The LDS
   form was LDS-port-bound: 4 waves x 14 ds_read_b128 per node-iter = 56 LDS
   instrs/node x ~12cyc x 19.5 nodes x 2 blk/CU ~= 26k cyc ~= 11us, for a
   loop-invariant per-thread operand. Registers delete that path + the barrier.
   x[n*14+k] is wave-uniform -> s_load. Bit-identical numerics. */
__global__ __launch_bounds__(256) void k_gemm1f(const float* __restrict__ x, const float* __restrict__ W1,
                                                const float* __restrict__ a_src, const float* __restrict__ a_dst,
                                                ushort_t* __restrict__ h1,
                                                float* __restrict__ alS, float* __restrict__ alD){
    int tid = threadIdx.x;
    int c0 = tid * 4;
    float4 w1r[14];
    #pragma unroll
    for (int k = 0; k < 14; k++) w1r[k] = *(const float4*)(W1 + k*HT + c0);
    float4 sv = *(const float4*)(a_src + c0);
    float4 dv = *(const float4*)(a_dst + c0);
    int head = tid >> 5, l32 = tid & 31;
    for (int n = blockIdx.x; n < N_NODES; n += gridDim.x){
        float a0=0.f, a1=0.f, a2=0.f, a3=0.f;
        #pragma unroll
        for (int k = 0; k < 14; k++){
            float xv = x[n*14 + k];
            float4 w = w1r[k];
            a0 += xv*w.x; a1 += xv*w.y; a2 += xv*w.z; a3 += xv*w.w;
        }
        uint2 o;
        o.x = (uint32)f2bf(a0) | ((uint32)f2bf(a1) << 16);
        o.y = (uint32)f2bf(a2) | ((uint32)f2bf(a3) << 16);
        *(uint2*)(h1 + (size_t)n*HT + c0) = o;
        float h0,h1v,h2,h3v;
        unpack2(o.x, h0, h1v); unpack2(o.y, h2, h3v);
        float s = h0*sv.x + h1v*sv.y + h2*sv.z + h3v*sv.w;
        float d = h0*dv.x + h1v*dv.y + h2*dv.z + h3v*dv.w;
        #pragma unroll
        for (int of = 16; of; of >>= 1){ s += __shfl_xor(s, of, 32); d += __shfl_xor(d, of, 32); }
        if (l32 == 0){ alS[n*HEADS + head] = s; alD[n*HEADS + head] = d; }
    }
}

/* ---------------- fused segment-softmax + aggregate + bias + relu (v5.3) ----------------
   Head-partitioned, XCD-affine gather (R4/R5): block b -> head = b&7; per-XCD
   H slice 2.56 MB (FETCH 146->15.7 MB, proven). VALU-bound (86-92%); v5.3 has
   pre-scaled srcs (s*8) and log2e-prescaled a-vectors -> bare v_exp_f32.
   At its measured structural floor (~46-49us across 3 formulations). */
__global__ __launch_bounds__(256) void k_gat_agg(const ushort_t* __restrict__ H, const float* __restrict__ alS,
                                                 const float* __restrict__ alD, const int* __restrict__ offs,
                                                 const int* __restrict__ srcs, const float* __restrict__ bias,
                                                 ushort_t* __restrict__ out){
    int tid = threadIdx.x;
    int wv = tid >> 6, lane = tid & 63;
    int head = blockIdx.x & 7;
    int n = (blockIdx.x >> 3) * 4 + wv;
    if (n >= N_NODES) return;
    int beg = offs[n], end = offs[n+1];
    int g = lane >> 4;           /* edge slot 0..3 */
    int q = lane & 15;           /* 8-channel sub-block within head */
    float ad = alD[n*HEADS + head];
    const ushort_t* Hh = H + head*128 + q*8;
    const float NINF = -__int_as_float(0x7f800000);

    float m = -1e30f, z = 0.f;
    float c0=0.f,c1=0.f,c2=0.f,c3=0.f,c4=0.f,c5=0.f,c6=0.f,c7=0.f;
    for (int c = beg; c < end; c += 64){
        int cn = min(64, end - c);
        int sreg = (lane < cn) ? srcs[c + lane] : 0;
        int j = 0;
        /* 8-edge body: e1 = j+4+g <= j+7 < cn, so no masking needed */
        for (; j + 8 <= cn; j += 8){
            int s0 = __shfl(sreg, j + g, 64);       /* = src*8 */
            int s1 = __shfl(sreg, j + 4 + g, 64);
            uint4 u0 = *(const uint4*)(Hh + (size_t)s0*128);
            uint4 u1 = *(const uint4*)(Hh + (size_t)s1*128);
            float v0 = alS[s0 + head] + ad; v0 = v0 > 0.f ? v0 : NEG*v0;
            float v1 = alS[s1 + head] + ad; v1 = v1 > 0.f ? v1 : NEG*v1;
            float vm = fmaxf(v0, v1);
            if (vm > m){
                float sc = EXP2(m - vm);
                z *= sc;
                c0*=sc; c1*=sc; c2*=sc; c3*=sc;
                c4*=sc; c5*=sc; c6*=sc; c7*=sc;
                m = vm;
            }
            float w0 = EXP2(v0 - m);
            float w1 = EXP2(v1 - m);
            z += (w0 + w1);
            float f0,f1,f2,f3,f4,f5,f6,f7;
            float g0,g1,g2,g3,g4,g5,g6,g7;
            unpack2(u0.x,f0,f1); unpack2(u0.y,f2,f3); unpack2(u0.z,f4,f5); unpack2(u0.w,f6,f7);
            unpack2(u1.x,g0,g1); unpack2(u1.y,g2,g3); unpack2(u1.z,g4,g5); unpack2(u1.w,g6,g7);
            c0 = fmaf(w0,f0, fmaf(w1,g0, c0));
            c1 = fmaf(w0,f1, fmaf(w1,g1, c1));
            c2 = fmaf(w0,f2, fmaf(w1,g2, c2));
            c3 = fmaf(w0,f3, fmaf(w1,g3, c3));
            c4 = fmaf(w0,f4, fmaf(w1,g4, c4));
            c5 = fmaf(w0,f5, fmaf(w1,g5, c5));
            c6 = fmaf(w0,f6, fmaf(w1,g6, c6));
            c7 = fmaf(w0,f7, fmaf(w1,g7, c7));
        }
        /* masked tail, 4 edges at a time */
        for (; j < cn; j += 4){
            int e = j + g;
            int s0 = __shfl(sreg, e, 64);
            uint4 u0 = *(const uint4*)(Hh + (size_t)s0*128);
            float v0 = alS[s0 + head] + ad; v0 = v0 > 0.f ? v0 : NEG*v0;
            v0 = (e < cn) ? v0 : NINF;          /* exp2(NINF - finite) == 0 */
            if (v0 > m){
                float sc = EXP2(m - v0);
                z *= sc;
                c0*=sc; c1*=sc; c2*=sc; c3*=sc;
                c4*=sc; c5*=sc; c6*=sc; c7*=sc;
                m = v0;
            }
            float w0 = EXP2(v0 - m);
            z += w0;
            float f0,f1,f2,f3,f4,f5,f6,f7;
            unpack2(u0.x,f0,f1); unpack2(u0.y,f2,f3); unpack2(u0.z,f4,f5); unpack2(u0.w,f6,f7);
            c0 = fmaf(w0,f0, c0); c1 = fmaf(w0,f1, c1);
            c2 = fmaf(w0,f2, c2); c3 = fmaf(w0,f3, c3);
            c4 = fmaf(w0,f4, c4); c5 = fmaf(w0,f5, c5);
            c6 = fmaf(w0,f6, c6); c7 = fmaf(w0,f7, c7);
        }
    }
    /* merge (m,z,c[8]) across the 4 edge-groups: xor 16 then 32 */
    #pragma unroll
    for (int off = 16; off < 64; off <<= 1){
        float m2 = __shfl_xor(m, off, 64);
        float z2 = __shfl_xor(z, off, 64);
        float d0 = __shfl_xor(c0, off, 64);
        float d1 = __shfl_xor(c1, off, 64);
        float d2 = __shfl_xor(c2, off, 64);
        float d3 = __shfl_xor(c3, off, 64);
        float d4 = __shfl_xor(c4, off, 64);
        float d5 = __shfl_xor(c5, off, 64);
        float d6 = __shfl_xor(c6, off, 64);
        float d7 = __shfl_xor(c7, off, 64);
        float nm = fmaxf(m, m2);
        float a = EXP2(m - nm), b = EXP2(m2 - nm);
        z = z*a + z2*b;
        c0 = c0*a + d0*b; c1 = c1*a + d1*b;
        c2 = c2*a + d2*b; c3 = c3*a + d3*b;
        c4 = c4*a + d4*b; c5 = c5*a + d5*b;
        c6 = c6*a + d6*b; c7 = c7*a + d7*b;
        m = nm;
    }
    if (g == 0){
        float inv = 1.f / (z + 1e-16f);
        int ch0 = head*128 + q*8;
        float4 b0 = *(const float4*)(bias + ch0);
        float4 b1 = *(const float4*)(bias + ch0 + 4);
        c0 = fmaxf(c0*inv+b0.x, 0.f); c1 = fmaxf(c1*inv+b0.y, 0.f);
        c2 = fmaxf(c2*inv+b0.z, 0.f); c3 = fmaxf(c3*inv+b0.w, 0.f);
        c4 = fmaxf(c4*inv+b1.x, 0.f); c5 = fmaxf(c5*inv+b1.y, 0.f);
        c6 = fmaxf(c6*inv+b1.z, 0.f); c7 = fmaxf(c7*inv+b1.w, 0.f);
        uint4 o;
        o.x = (uint32)f2bf(c0) | ((uint32)f2bf(c1) << 16);
        o.y = (uint32)f2bf(c2) | ((uint32)f2bf(c3) << 16);
        o.z = (uint32)f2bf(c4) | ((uint32)f2bf(c5) << 16);
        o.w = (uint32)f2bf(c6) | ((uint32)f2bf(c7) << 16);
        *(uint4*)(out + (size_t)n*HT + ch0) = o;
    }
}

/* ---------------- layer-2 GEMM: bf16 MFMA, fused attention dots (v4) ----------------
   8 waves (512 threads), wave owns 64x32 of the 128x128 tile (R5). BK=64
   2-phase double-buffered pipeline; attention-dot epilogue combines 4
   wn-waves via LDS partials. */
__global__ __launch_bounds__(512) void k_gemm2(const ushort_t* __restrict__ A, const ushort_t* __restrict__ BT,
                                               ushort_t* __restrict__ C,
                                               const float* __restrict__ aS, const float* __restrict__ aD,
                                               float* __restrict__ alS, float* __restrict__ alD){
    __shared__ ushort_t lbuf[2][2][128*64];       /* [buf][0=A,1=B][row*64+e] : 64 KiB */
    float (*reds)[3][64][2] = (float (*)[3][64][2])lbuf; /* [wm6][widx][rl][s/d], aliased after K-loop */
    int L = blockIdx.x;
    int xcd = L & 7;
    int wi  = L >> 3;
    int bm  = xcd * 10 + (wi >> 3);
    int bn  = wi & 7;
    if (bm >= 79) return;
    int tid = threadIdx.x;
    int lane = tid & 63;
    int wave = tid >> 6;                  /* 0..7 */
    int wm  = (wave & 1) * 64;            /* row half */
    int wn32 = (wave >> 1) * 32;          /* 32-col strip */
    int lm = lane & 15, kg = lane >> 4;
    int c0 = (kg ^ (lm & 7)) * 8;    /* phys elem offset of ksub0 fragment; ksub1 = c0^32 */
    f32x4 acc[4][2];
    #pragma unroll
    for (int i = 0; i < 4; i++)
        #pragma unroll
        for (int j = 0; j < 2; j++) acc[i][j] = (f32x4)0.0f;

    const int K = 1024;
    int rowA0 = bm * 128, rowB0 = bn * 128;

    auto stage = [&](int buf, int k0){
        #pragma unroll
        for (int it = 0; it < 2; ++it){
            int s = tid + it*512;           /* chunk id in [0,1024): row = s>>3, phys chunk = s&7 */
            int r = s >> 3;
            int q = (s & 7) ^ (r & 7);      /* logical chunk living at this phys slot */
            gload_lds16(A  + (size_t)(rowA0 + r)*K + k0 + q*8, &lbuf[buf][0][s*8]);
            gload_lds16(BT + (size_t)(rowB0 + r)*K + k0 + q*8, &lbuf[buf][1][s*8]);
        }
    };

    stage(0, 0);
    asm volatile("s_waitcnt vmcnt(0)" ::: "memory");
    __syncthreads();
    int cur = 0;
    for (int k0 = 0; k0 < K; k0 += 64){
        if (k0 + 64 < K) stage(cur ^ 1, k0 + 64);   /* prefetch next tile first */
        bf16x8 a0[4], a1[4], b0[2], b1[2];
        #pragma unroll
        for (int mt = 0; mt < 4; mt++){
            const ushort_t* base = &lbuf[cur][0][(wm + mt*16 + lm)*64];
            a0[mt] = *(const bf16x8*)(base + c0);
            a1[mt] = *(const bf16x8*)(base + (c0 ^ 32));
        }
        #pragma unroll
        for (int nt = 0; nt < 2; nt++){
            const ushort_t* base = &lbuf[cur][1][(wn32 + nt*16 + lm)*64];
            b0[nt] = *(const bf16x8*)(base + c0);
            b1[nt] = *(const bf16x8*)(base + (c0 ^ 32));
        }
        #pragma unroll
        for (int mt = 0; mt < 4; mt++)
            #pragma unroll
            for (int nt = 0; nt < 2; nt++)
                acc[mt][nt] = __builtin_amdgcn_mfma_f32_16x16x32_bf16(a0[mt], b0[nt], acc[mt][nt], 0, 0, 0);
        #pragma unroll
        for (int mt = 0; mt < 4; mt++)
            #pragma unroll
            for (int nt = 0; nt < 2; nt++)
                acc[mt][nt] = __builtin_amdgcn_mfma_f32_16x16x32_bf16(a1[mt], b1[nt], acc[mt][nt], 0, 0, 0);
        asm volatile("s_waitcnt vmcnt(0)" ::: "memory");
        __syncthreads();
        cur ^= 1;
    }
    #pragma unroll
    for (int mt = 0; mt < 4; mt++){
        int row_base = bm*128 + wm + mt*16 + kg*4;
        #pragma unroll
        for (int nt = 0; nt < 2; nt++){
            int col = bn*128 + wn32 + nt*16 + lm;
            #pragma unroll
            for (int r = 0; r < 4; r++){
                int row = row_base + r;
                if (row < N_NODES) C[(size_t)row*HT + col] = f2bf(acc[mt][nt][r]);
            }
        }
    }
    /* fused attention-dot epilogue for head bn: wave partial over its 32 cols,
       combine 4 wn-waves through LDS partials */
    float as_l[2], ad_l[2];
    #pragma unroll
    for (int nt = 0; nt < 2; nt++){
        as_l[nt] = aS[bn*128 + wn32 + nt*16 + lm];
        ad_l[nt] = aD[bn*128 + wn32 + nt*16 + lm];
    }
    float psA[4][4], pdA[4][4];
    #pragma unroll
    for (int mt = 0; mt < 4; mt++){
        #pragma unroll
        for (int r = 0; r < 4; r++){
            float ps = acc[mt][0][r]*as_l[0] + acc[mt][1][r]*as_l[1];
            float pd = acc[mt][0][r]*ad_l[0] + acc[mt][1][r]*ad_l[1];
            #pragma unroll
            for (int o = 1; o < 16; o <<= 1){ ps += __shfl_xor(ps, o, 64); pd += __shfl_xor(pd, o, 64); }
            psA[mt][r] = ps; pdA[mt][r] = pd;
            if (wn32 != 0 && lm == 0){
                int rl = mt*16 + kg*4 + r;
                reds[wm >> 6][(wn32 >> 5) - 1][rl][0] = ps;
                reds[wm >> 6][(wn32 >> 5) - 1][rl][1] = pd;
            }
        }
    }
    __syncthreads();
    if (wn32 == 0 && lm == 0){
        #pragma unroll
        for (int mt = 0; mt < 4; mt++){
            #pragma unroll
            for (int r = 0; r < 4; r++){
                int rl = mt*16 + kg*4 + r;
                int row = bm*128 + wm + rl;
                if (row < N_NODES){
                    alS[row*HEADS + bn] = psA[mt][r] + reds[wm >> 6][0][rl][0]
                                        + reds[wm >> 6][1][rl][0] + reds[wm >> 6][2][rl][0];
                    alD[row*HEADS + bn] = pdA[mt][r] + reds[wm >> 6][0][rl][1]
                                        + reds[wm >> 6][1][rl][1] + reds[wm >> 6][2][rl][1];
                }
            }
        }
    }
}

/* ---------------- layer-3 GEMM: wave-per-node, W3 in registers ---------------- */
__global__ __launch_bounds__(256) void k_gemm3(const ushort_t* __restrict__ A, const float* __restrict__ W3,
                                               const float* __restrict__ s3,
                                               float* __restrict__ h3, float* __restrict__ al3s, float* __restrict__ al3d){
    int tid = threadIdx.x;
    int lane = tid & 63, wave = tid >> 6;
    int n = blockIdx.x * 4 + wave;
    if (n >= N_NODES) return;
    float4 w3r[16];
    #pragma unroll
    for (int j = 0; j < 16; j++) w3r[j] = ((const float4*)W3)[lane*16 + j];
    const uint4* ap = (const uint4*)(A + (size_t)n*HT + lane*16);
    uint4 u0 = ap[0], u1 = ap[1];
    uint32 uu[8] = {u0.x,u0.y,u0.z,u0.w,u1.x,u1.y,u1.z,u1.w};
    float acc0=0.f, acc1=0.f, acc2=0.f, acc3=0.f;
    #pragma unroll
    for (int p = 0; p < 8; p++){
        float lo, hi;
        unpack2(uu[p], lo, hi);
        float4 wl = w3r[p*2], wh = w3r[p*2+1];
        acc0 += lo*wl.x + hi*wh.x;
        acc1 += lo*wl.y + hi*wh.y;
        acc2 += lo*wl.z + hi*wh.z;
        acc3 += lo*wl.w + hi*wh.w;
    }
    #pragma unroll
    for (int o = 32; o; o >>= 1){
        acc0 += __shfl_xor(acc0, o, 64); acc1 += __shfl_xor(acc1, o, 64);
        acc2 += __shfl_xor(acc2, o, 64); acc3 += __shfl_xor(acc3, o, 64);
    }
    if (lane == 0){
        *(float4*)(h3 + n*4) = make_float4(acc0, acc1, acc2, acc3);
        al3s[n] = acc0*s3[0] + acc1*s3[1] + acc2*s3[2] + acc3*s3[3];
        al3d[n] = acc0*s3[16] + acc1*s3[17] + acc2*s3[18] + acc3*s3[19];
    }
}

/* ---------------- layer-3 attention aggregate: wave-per-node ----------------
   srcs pre-scaled (s*8): al3s index = sp>>3, h3 float index = sp>>1.
   al3s/al3d pre-scaled by log2e (as3/ad3 scaled at setup) -> exp2. */
__global__ __launch_bounds__(256) void k_gat_agg3(const float* __restrict__ h3, const float* __restrict__ al3s,
                                                  const float* __restrict__ al3d, const int* __restrict__ offs,
                                                  const int* __restrict__ srcs, const float* __restrict__ b3,
                                                  const int* __restrict__ flags, void* __restrict__ out){
    int tid = threadIdx.x;
    int l = tid & 63, wave = tid >> 6;
    int n = blockIdx.x * 4 + wave;
    if (n >= N_NODES) return;
    int beg = offs[n], end = offs[n+1];
    float ad = al3d[n];
    float m = -1e30f;
    for (int e = beg + l; e < end; e += 64){
        float v = al3s[srcs[e] >> 3] + ad; v = v > 0.f ? v : NEG*v;
        m = fmaxf(m, v);
    }
    #pragma unroll
    for (int o = 32; o; o >>= 1) m = fmaxf(m, __shfl_xor(m, o, 64));
    float z = 0.f;
    for (int e = beg + l; e < end; e += 64){
        float v = al3s[srcs[e] >> 3] + ad; v = v > 0.f ? v : NEG*v;
        z += EXP2(v - m);
    }
    #pragma unroll
    for (int o = 32; o; o >>= 1) z += __shfl_xor(z, o, 64);
    float inv = 1.f / (z + 1e-16f);
    float a0=0.f, a1=0.f, a2=0.f, a3=0.f;
    for (int e = beg + l; e < end; e += 64){
        int sp = srcs[e];
        float v = al3s[sp >> 3] + ad; v = v > 0.f ? v : NEG*v;
        float w = EXP2(v - m) * inv;
        float4 hv = *(const float4*)(h3 + (sp >> 1));
        a0 += w*hv.x; a1 += w*hv.y; a2 += w*hv.z; a3 += w*hv.w;
    }
    #pragma unroll
    for (int o = 32; o; o >>= 1){
        a0 += __shfl_xor(a0, o, 64); a1 += __shfl_xor(a1, o, 64);
        a2 += __shfl_xor(a2, o, 64); a3 += __shfl_xor(a3, o, 64);
    }
    if (l == 0){
        float r0 = fmaxf(a0 + b3[0], 0.f);
        float r1 = fmaxf(a1 + b3[1], 0.f);
        float r2 = fmaxf(a2 + b3[2], 0.f);
        float r3 = fmaxf(a3 + b3[3], 0.f);
        if (flags[1]){
            float* o4 = (float*)out;
            o4[n*4+0]=r0; o4[n*4+1]=r1; o4[n*4+2]=r2; o4[n*4+3]=r3;
        } else {
            ushort_t* o2 = (ushort_t*)out;
            o2[n*4+0]=f2bf(r0); o2[n*4+1]=f2bf(r1); o2[n*4+2]=f2bf(r2); o2[n*4+3]=f2bf(r3);
        }
    }
}

extern "C" void kernel_launch(void* const* d_in, const int* in_sizes, int n_in,
                              void* d_out, int out_size, void* d_ws, size_t ws_size,
                              hipStream_t stream){
    const void* x   = d_in[0];
    const void* ei  = d_in[1];
    const void* W1  = d_in[2];
    const void* as1 = d_in[3];
    const void* ad1 = d_in[4];
    const void* b1  = d_in[5];
    const void* W2  = d_in[6];
    const void* as2 = d_in[7];
    const void* ad2 = d_in[8];
    const void* b2  = d_in[9];
    const void* W3  = d_in[10];
    const void* as3 = d_in[11];
    const void* ad3 = d_in[12];
    const void* b3  = d_in[13];

    char* ws = (char*)d_ws;
    int* flags     = (int*)(ws + O_FLAG);
    int* srcA      = (int*)(ws + O_SRC);
    int* dstA      = (int*)(ws + O_DST);
    int* counts    = (int*)(ws + O_COUNTS);
    int* offs      = (int*)(ws + O_OFFS);
    int* cursors   = (int*)(ws + O_CURS);
    int* ssort     = (int*)(ws + O_SSORT);
    float* alS     = (float*)(ws + O_ALS);
    float* alD     = (float*)(ws + O_ALD);
    float* al3s    = (float*)(ws + O_AL3S);
    float* al3d    = (float*)(ws + O_AL3D);
    float* h3      = (float*)(ws + O_H3);
    float* xF      = (float*)(ws + O_XF);
    float* W1F     = (float*)(ws + O_W1F);
    float* wvecF   = (float*)(ws + O_AS1F);
    float* W3F     = (float*)(ws + O_W3F);
    float* s3F     = (float*)(ws + O_S3F);
    ushort_t* W2T  = (ushort_t*)(ws + O_W2T);
    ushort_t* bufA = (ushort_t*)(ws + O_BUFA);
    ushort_t* bufB = (ushort_t*)(ws + O_BUFB);

    const int EB = (ET + 255) / 256;

    CvtArgs ca;
    ca.src[0]=x;   ca.dst[0]=xF;            ca.n[0]=140000;  ca.scl[0]=1.0f;
    ca.src[1]=W1;  ca.dst[1]=W1F;           ca.n[1]=14336;   ca.scl[1]=1.0f;
    ca.src[2]=as1; ca.dst[2]=wvecF+0*1024;  ca.n[2]=1024;    ca.scl[2]=LOG2E;
    ca.src[3]=ad1; ca.dst[3]=wvecF+1*1024;  ca.n[3]=1024;    ca.scl[3]=LOG2E;
    ca.src[4]=b1;  ca.dst[4]=wvecF+2*1024;  ca.n[4]=1024;    ca.scl[4]=1.0f;
    ca.src[5]=as2; ca.dst[5]=wvecF+3*1024;  ca.n[5]=1024;    ca.scl[5]=LOG2E;
    ca.src[6]=ad2; ca.dst[6]=wvecF+4*1024;  ca.n[6]=1024;    ca.scl[6]=LOG2E;
    ca.src[7]=b2;  ca.dst[7]=wvecF+5*1024;  ca.n[7]=1024;    ca.scl[7]=1.0f;
    ca.src[8]=W3;  ca.dst[8]=W3F;           ca.n[8]=4096;    ca.scl[8]=1.0f;
    ca.src[9]=as3; ca.dst[9]=s3F+0;         ca.n[9]=4;       ca.scl[9]=LOG2E;
    ca.src[10]=ad3; ca.dst[10]=s3F+16;      ca.n[10]=4;      ca.scl[10]=LOG2E;
    ca.src[11]=b3;  ca.dst[11]=s3F+32;      ca.n[11]=4;      ca.scl[11]=1.0f;

    k_probe<<<1, 64, 0, stream>>>((const uint32*)W1, (const int*)ei, flags);
    k_setup<<<dim3(1024, 14), 256, 0, stream>>>(ca, W2, counts, W2T, flags);
    k_extract_hist<<<EB, 256, 0, stream>>>(ei, flags, srcA, dstA, counts);
    k_scan<<<1, 1024, 0, stream>>>(counts, offs, cursors, N_NODES);
    k_scatter<<<EB, 256, 0, stream>>>(srcA, dstA, cursors, ssort);

    /* layer 1 (gemm + dots fused); agg: 8 heads x 2500 node-groups, head = bid&7 -> XCD-affine */
    k_gemm1f<<<512, 256, 0, stream>>>(xF, W1F, wvecF+0*1024, wvecF+1*1024, bufA, alS, alD);
    k_gat_agg<<<20000, 256, 0, stream>>>(bufA, alS, alD, offs, ssort, wvecF+2*1024, bufB);

    /* layer 2 (gemm + dots fused, XCD-swizzled linear grid, 8-wave 2-phase dbuf) */
    k_gemm2<<<640, 512, 0, stream>>>(bufB, W2T, bufA, wvecF+3*1024, wvecF+4*1024, alS, alD);
    k_gat_agg<<<20000, 256, 0, stream>>>(bufA, alS, alD, offs, ssort, wvecF+5*1024, bufB);

    /* layer 3 */
    k_gemm3<<<2500, 256, 0, stream>>>(bufB, W3F, s3F, h3, al3s, al3d);
    k_gat_agg3<<<2500, 256, 0, stream>>>(h3, al3s, al3d, offs, ssort, s3F+32, flags, d_out);
}